// Round 3
// baseline (690.154 us; speedup 1.0000x reference)
//
#include <hip/hip_runtime.h>
#include <math.h>

namespace {
constexpr int BATCH = 32;
constexpr int NANCH = 15130;
constexpr int NPAIR = NANCH / 2;   // 7565
constexpr int NCLS  = 81;
constexpr int C1    = 80;          // foreground classes
constexpr int MAXO  = 200;
constexpr int CAP   = 1024;        // LDS sort capacity per (b, class)
constexpr int CAPB  = 768;         // global bucket capacity (mean 434, sigma 20.5)
constexpr int NWORD = 4;           // 256 bits >= 200 for NMS bitmask
constexpr int NBIN  = 2048;        // histogram bins for final top-k select
constexpr unsigned BINBASE = 0x3D000000u;  // 0.03125f — below any score > 0.05
}

#define SCORE_TH 0.05f
#define IOU_TH   0.5f

// Descending bitonic sort of P (power of 2) u64 keys in LDS.
// Key = (float_bits(score) << 32) | (0xFFFFFFFF - index)
// => order: score desc, then index asc (matches jax.lax.top_k stability).
__device__ __forceinline__ void bitonic_desc(unsigned long long* keys, int P,
                                             int tid, int nthr) {
    for (int k = 2; k <= P; k <<= 1) {
        for (int j = k >> 1; j > 0; j >>= 1) {
            for (int i = tid; i < P; i += nthr) {
                int ixj = i ^ j;
                if (ixj > i) {
                    unsigned long long a = keys[i], c = keys[ixj];
                    bool up = ((i & k) == 0);
                    if (up ? (a < c) : (a > c)) { keys[i] = c; keys[ixj] = a; }
                }
            }
            __syncthreads();
        }
    }
}

__device__ __forceinline__ float iou_f(float al, float at, float ar, float ab,
                                       float bl, float bt, float br, float bb) {
#pragma clang fp contract(off)
    float l = fmaxf(al, bl);
    float t = fmaxf(at, bt);
    float r = fminf(ar, br);
    float d = fminf(ab, bb);
    float w = fmaxf(r - l, 0.f);
    float h = fmaxf(d - t, 0.f);
    float inter = w * h;
    float areaa = (ar - al) * (ab - at);
    float areab = (br - bl) * (bb - bt);
    return inter / (areaa + areab - inter + 1e-12f);
}

// Kernel 0: zero the per-(b,class) bucket counters.
__global__ __launch_bounds__(256) void ssd_zero_cnt(int* __restrict__ cntg) {
    int i = blockIdx.x * 256 + threadIdx.x;
    if (i < BATCH * C1) cntg[i] = 0;
}

// Kernel 1: decode boxes + per-(b,n) softmax stats + push candidates with
// prob > SCORE_TH into per-(b,class) global buckets. One thread = 2 anchors.
__global__ __launch_bounds__(256) void ssd_decode_stats(
    const float* __restrict__ ploc, const float* __restrict__ plabel,
    const float* __restrict__ dboxes,
    float* __restrict__ ltrb, float* __restrict__ rowmax,
    float* __restrict__ rowsum,
    int* __restrict__ cntg, unsigned long long* __restrict__ bucket) {
#pragma clang fp contract(off)
    int idx2 = blockIdx.x * 256 + threadIdx.x;
    if (idx2 >= BATCH * NPAIR) return;
    int b = idx2 / NPAIR, pr = idx2 - b * NPAIR;
    int n0 = pr * 2;

    // ---- decode two anchors ----
    const float* pl = ploc + (size_t)b * 4 * NANCH + n0;
    float2 pxy = *reinterpret_cast<const float2*>(pl);
    float2 pyy = *reinterpret_cast<const float2*>(pl + NANCH);
    float2 pww = *reinterpret_cast<const float2*>(pl + 2 * NANCH);
    float2 phh = *reinterpret_cast<const float2*>(pl + 3 * NANCH);
    for (int t = 0; t < 2; ++t) {
        int n = n0 + t;
        float px = t ? pxy.y : pxy.x;
        float py = t ? pyy.y : pyy.x;
        float pw = t ? pww.y : pww.x;
        float ph = t ? phh.y : phh.x;
        float4 db = reinterpret_cast<const float4*>(dboxes)[n];
        float cx = px * 0.1f * db.z + db.x;
        float cy = py * 0.1f * db.w + db.y;
        float w  = expf(pw * 0.2f) * db.z;
        float h  = expf(ph * 0.2f) * db.w;
        float4 o;
        o.x = cx - 0.5f * w; o.y = cy - 0.5f * h;
        o.z = cx + 0.5f * w; o.w = cy + 0.5f * h;
        reinterpret_cast<float4*>(ltrb)[(size_t)b * NANCH + n] = o;
    }

    // ---- softmax stats: exact 2-pass (same op order as reference) ----
    const float* pb = plabel + (size_t)b * NCLS * NANCH + n0;
    float m0 = -INFINITY, m1 = -INFINITY;
    for (int c = 0; c < NCLS; ++c) {
        float2 v = *reinterpret_cast<const float2*>(pb + (size_t)c * NANCH);
        m0 = fmaxf(m0, v.x);
        m1 = fmaxf(m1, v.y);
    }
    float s0 = 0.f, s1 = 0.f;
    for (int c = 0; c < NCLS; ++c) {
        float2 v = *reinterpret_cast<const float2*>(pb + (size_t)c * NANCH);
        s0 += expf(v.x - m0);
        s1 += expf(v.y - m1);
    }
    size_t ridx = (size_t)b * NANCH + n0;
    *reinterpret_cast<float2*>(rowmax + ridx) = make_float2(m0, m1);
    *reinterpret_cast<float2*>(rowsum + ridx) = make_float2(s0, s1);

    // ---- candidate push: p = expf(x - m) / s  (bit-identical to prior K2) ----
    for (int c = 1; c < NCLS; ++c) {
        float2 v = *reinterpret_cast<const float2*>(pb + (size_t)c * NANCH);
        float p0 = expf(v.x - m0) / s0;
        float p1 = expf(v.y - m1) / s1;
        int bc = b * C1 + (c - 1);
        if (p0 > SCORE_TH) {
            int pos = atomicAdd(&cntg[bc], 1);
            if (pos < CAPB)
                bucket[(size_t)bc * CAPB + pos] =
                    ((unsigned long long)__float_as_uint(p0) << 32)
                    | (unsigned long long)(0xFFFFFFFFu - (unsigned)n0);
        }
        if (p1 > SCORE_TH) {
            int pos = atomicAdd(&cntg[bc], 1);
            if (pos < CAPB)
                bucket[(size_t)bc * CAPB + pos] =
                    ((unsigned long long)__float_as_uint(p1) << 32)
                    | (unsigned long long)(0xFFFFFFFFu - (unsigned)(n0 + 1));
        }
    }
}

// Kernel 2: per (b, class): exact top-200 of its bucket + greedy NMS (bitmask).
__global__ __launch_bounds__(256) void ssd_class_nms(
    const float* __restrict__ plabel, const float* __restrict__ rowmax,
    const float* __restrict__ rowsum, const float* __restrict__ ltrb,
    const int* __restrict__ cntg, const unsigned long long* __restrict__ bucket,
    float* __restrict__ pcVals, float* __restrict__ pcBoxes) {
    __shared__ unsigned long long keys[CAP];
    __shared__ float bxl[MAXO], bxt[MAXO], bxr[MAXO], bxb[MAXO], vs[MAXO];
    __shared__ unsigned long long sup[MAXO][NWORD];
    __shared__ unsigned long long keepw[NWORD];
    __shared__ int scanbuf[256];
    __shared__ int cnt, fillcnt;

    const int tid = threadIdx.x;
    const int b   = blockIdx.x / C1;
    const int cls = blockIdx.x % C1 + 1;   // skip background
    const int bc  = b * C1 + (cls - 1);

    if (tid == 0) { cnt = 0; fillcnt = 0; }
    __syncthreads();

    const float* pl = plabel + ((size_t)b * NCLS + cls) * NANCH;
    const float* rm = rowmax + (size_t)b * NANCH;
    const float* rs = rowsum + (size_t)b * NANCH;

    const int gcount = cntg[bc];
    int count;
    if (gcount <= CAPB) {
        // Fast path: bucket holds all candidates.
        for (int i = tid; i < gcount; i += 256)
            keys[i] = bucket[(size_t)bc * CAPB + i];
        count = gcount;
        __syncthreads();
    } else {
        // Overflow fallback (dead in practice): full rescan.
        for (int n = tid; n < NANCH; n += 256) {
            float p = expf(pl[n] - rm[n]) / rs[n];
            if (p > SCORE_TH) {
                int pos = atomicAdd(&cnt, 1);
                if (pos < CAP)
                    keys[pos] = ((unsigned long long)__float_as_uint(p) << 32)
                              | (unsigned long long)(0xFFFFFFFFu - (unsigned)n);
            }
        }
        __syncthreads();
        count = min(cnt, CAP);
    }

    int P = 256; while (P < count) P <<= 1;
    for (int i = count + tid; i < P; i += 256) keys[i] = 0ull;
    __syncthreads();
    bitonic_desc(keys, P, tid, 256);

    // If fewer than 200 positives, fill with smallest anchor indices having
    // prob <= TH (replicates top_k tie-breaking among zeros). Dead in practice.
    if (count < MAXO) {
        const int need = MAXO - count;
        for (int base = 0; base < NANCH; base += 256) {
            if (fillcnt >= need) break;   // uniform (LDS, synced)
            int n = base + tid;
            int flag = 0;
            if (n < NANCH) {
                float p = expf(pl[n] - rm[n]) / rs[n];
                flag = (p <= SCORE_TH) ? 1 : 0;
            }
            scanbuf[tid] = flag;
            __syncthreads();
            for (int off = 1; off < 256; off <<= 1) {
                int v  = scanbuf[tid];
                int vp = (tid >= off) ? scanbuf[tid - off] : 0;
                __syncthreads();
                scanbuf[tid] = v + vp;
                __syncthreads();
            }
            int excl = scanbuf[tid] - flag;
            if (flag && (fillcnt + excl) < need)
                keys[count + fillcnt + excl] =
                    (unsigned long long)(0xFFFFFFFFu - (unsigned)n);
            __syncthreads();
            if (tid == 0) fillcnt += scanbuf[255];
            __syncthreads();
        }
        __syncthreads();
    }

    // Gather top-200 boxes/scores into LDS
    for (int t = tid; t < MAXO; t += 256) {
        unsigned long long key = keys[t];
        float sc   = __uint_as_float((unsigned)(key >> 32));
        unsigned n = 0xFFFFFFFFu - (unsigned)(key & 0xFFFFFFFFull);
        const float4 bb =
            reinterpret_cast<const float4*>(ltrb)[(size_t)b * NANCH + n];
        bxl[t] = bb.x; bxt[t] = bb.y; bxr[t] = bb.z; bxb[t] = bb.w;
        vs[t] = sc;
    }
    __syncthreads();

    // Parallel suppression bit-matrix: sup[i] bit j set iff j>i && IoU>=TH.
    for (int task = tid; task < MAXO * NWORD; task += 256) {
        int i = task >> 2;
        int w = task & (NWORD - 1);
        unsigned long long m = 0ull;
        int jbase = w * 64;
        if (jbase + 63 > i) {
            float al = bxl[i], at = bxt[i], ar = bxr[i], ab = bxb[i];
            int j0 = (jbase > i + 1) ? jbase : i + 1;
            int j1 = (jbase + 64 < MAXO) ? jbase + 64 : MAXO;
            for (int j = j0; j < j1; ++j) {
                float iou = iou_f(al, at, ar, ab,
                                  bxl[j], bxt[j], bxr[j], bxb[j]);
                if (iou >= IOU_TH) m |= 1ull << (j - jbase);
            }
        }
        sup[i][w] = m;
    }
    __syncthreads();

    // Serial greedy propagation (exactly the reference fori_loop recurrence).
    if (tid == 0) {
        unsigned long long k0 = ~0ull, k1 = ~0ull, k2 = ~0ull, k3 = ~0ull;
        for (int i = 0; i < MAXO; ++i) {
            unsigned long long kw = (i < 64) ? k0 : (i < 128) ? k1
                                  : (i < 192) ? k2 : k3;
            if (((kw >> (i & 63)) & 1ull) && vs[i] > 0.f) {
                k0 &= ~sup[i][0]; k1 &= ~sup[i][1];
                k2 &= ~sup[i][2]; k3 &= ~sup[i][3];
            }
        }
        keepw[0] = k0; keepw[1] = k1; keepw[2] = k2; keepw[3] = k3;
    }
    __syncthreads();

    float* pv  = pcVals  + (size_t)bc * MAXO;
    float* pbx = pcBoxes + (size_t)bc * MAXO * 4;
    for (int t = tid; t < MAXO; t += 256) {
        bool kp = (keepw[t >> 6] >> (t & 63)) & 1ull;
        pv[t] = (kp && vs[t] > 0.f) ? vs[t] : 0.f;
        pbx[t * 4 + 0] = bxl[t];
        pbx[t * 4 + 1] = bxt[t];
        pbx[t * 4 + 2] = bxr[t];
        pbx[t * 4 + 3] = bxb[t];
    }
}

// Kernel 3: per image, exact top-200 over the 80*200 flat list via
// histogram cutoff selection + small exact sort.
__global__ __launch_bounds__(256) void ssd_final_topk(
    const float* __restrict__ pcVals, const float* __restrict__ pcBoxes,
    float* __restrict__ out) {
    __shared__ unsigned int hist[NBIN];
    __shared__ int part[256];
    __shared__ unsigned long long cand[CAP];
    __shared__ int cnt, cutbin, nztot;

    const int tid = threadIdx.x;
    const int b   = blockIdx.x;
    const int TOT = C1 * MAXO;   // 16000
    const float* pv = pcVals + (size_t)b * TOT;

    for (int i = tid; i < NBIN; i += 256) hist[i] = 0u;
    if (tid == 0) { cnt = 0; cutbin = 1; }
    __syncthreads();

    // Pass 1: histogram of nonzero scores (bin mapping monotone in value).
    for (int g = tid; g < TOT; g += 256) {
        float v = pv[g];
        if (v > 0.f) {
            unsigned bits = __float_as_uint(v);
            unsigned bin = ((bits - BINBASE) >> 15) + 1u;
            if (bin > NBIN - 1) bin = NBIN - 1;
            atomicAdd(&hist[bin], 1u);
        }
    }
    __syncthreads();

    // Suffix sums over bins: thread t owns bins [t*8, t*8+8).
    int base = tid * 8;
    int loc = 0;
    for (int k = 0; k < 8; ++k) loc += (int)hist[base + k];
    part[tid] = loc;
    __syncthreads();
    for (int off = 1; off < 256; off <<= 1) {
        int v   = part[tid];
        int add = (tid + off < 256) ? part[tid + off] : 0;
        __syncthreads();
        part[tid] = v + add;
        __syncthreads();
    }
    if (tid == 0) nztot = part[0];
    {
        int suf = (tid + 1 < 256) ? part[tid + 1] : 0;
        int S = suf;
        for (int k = 7; k >= 0; --k) {
            int binv = (int)hist[base + k];
            int Sk = S + binv;
            int bin = base + k;
            if (bin >= 1 && Sk >= MAXO && S < MAXO) cutbin = bin;
            S = Sk;
        }
    }
    __syncthreads();
    int B = (nztot >= MAXO) ? cutbin : 1;

    // Pass 2: gather candidates in bins >= B.
    for (int g = tid; g < TOT; g += 256) {
        float v = pv[g];
        if (v > 0.f) {
            unsigned bits = __float_as_uint(v);
            unsigned bin = ((bits - BINBASE) >> 15) + 1u;
            if (bin > NBIN - 1) bin = NBIN - 1;
            if ((int)bin >= B) {
                int pos = atomicAdd(&cnt, 1);
                if (pos < CAP)
                    cand[pos] = ((unsigned long long)bits << 32)
                              | (unsigned long long)(0xFFFFFFFFu - (unsigned)g);
            }
        }
    }
    __syncthreads();
    int count = min(cnt, CAP);

    // Zero-fill (only if fewer than 200 nonzero in the whole image — dead path).
    if (count < MAXO) {
        if (tid == 0) {
            int c = count;
            for (int g = 0; g < TOT && c < MAXO; ++g) {
                if (!(pv[g] > 0.f)) {
                    cand[c++] = (unsigned long long)(0xFFFFFFFFu - (unsigned)g);
                }
            }
            cnt = c;
        }
        __syncthreads();
        count = min(cnt, CAP);
    }

    int P = 256; while (P < count) P <<= 1;
    for (int i = count + tid; i < P; i += 256) cand[i] = 0ull;
    __syncthreads();
    bitonic_desc(cand, P, tid, 256);

    for (int t = tid; t < MAXO; t += 256) {
        unsigned long long key = cand[t];
        float sc      = __uint_as_float((unsigned)(key >> 32));
        unsigned flat = 0xFFFFFFFFu - (unsigned)(key & 0xFFFFFFFFull);
        int cls = (int)(flat / MAXO) + 1;
        const float4 bb =
            reinterpret_cast<const float4*>(pcBoxes)[(size_t)b * TOT + flat];
        reinterpret_cast<float4*>(out)[(size_t)b * MAXO + t] = bb;
        out[(size_t)BATCH * MAXO * 4 + (size_t)b * MAXO + t] = (float)cls;
        out[(size_t)BATCH * MAXO * 5 + (size_t)b * MAXO + t] = sc;
    }
}

extern "C" void kernel_launch(void* const* d_in, const int* in_sizes, int n_in,
                              void* d_out, int out_size, void* d_ws,
                              size_t ws_size, hipStream_t stream) {
    const float* ploc   = (const float*)d_in[0];
    const float* plabel = (const float*)d_in[1];
    const float* dboxes = (const float*)d_in[2];
    float* out = (float*)d_out;

    float* ws      = (float*)d_ws;
    float* ltrb    = ws;                                   // B*N*4
    float* rowmax  = ltrb   + (size_t)BATCH * NANCH * 4;   // B*N
    float* rowsum  = rowmax + (size_t)BATCH * NANCH;       // B*N
    float* pcVals  = rowsum + (size_t)BATCH * NANCH;       // B*80*200
    float* pcBoxes = pcVals + (size_t)BATCH * C1 * MAXO;   // B*80*200*4
    int*   cntg    = (int*)(pcBoxes + (size_t)BATCH * C1 * MAXO * 4);
    unsigned long long* bucket =
        (unsigned long long*)(((char*)(cntg + BATCH * C1)) +
                              ((16 - (((size_t)(cntg + BATCH * C1)) & 15)) & 15));

    ssd_zero_cnt<<<(BATCH * C1 + 255) / 256, 256, 0, stream>>>(cntg);
    int npair = BATCH * NPAIR;
    ssd_decode_stats<<<(npair + 255) / 256, 256, 0, stream>>>(
        ploc, plabel, dboxes, ltrb, rowmax, rowsum, cntg, bucket);
    ssd_class_nms<<<BATCH * C1, 256, 0, stream>>>(
        plabel, rowmax, rowsum, ltrb, cntg, bucket, pcVals, pcBoxes);
    ssd_final_topk<<<BATCH, 256, 0, stream>>>(pcVals, pcBoxes, out);
}

// Round 4
// 630.178 us; speedup vs baseline: 1.0952x; 1.0952x over previous
//
#include <hip/hip_runtime.h>
#include <math.h>

namespace {
constexpr int BATCH = 32;
constexpr int NANCH = 15130;
constexpr int NCLS  = 81;
constexpr int C1    = 80;          // foreground classes
constexpr int MAXO  = 200;
constexpr int TPB   = 128;         // anchors per K1 block (= threads)
constexpr int NBLK  = (NANCH + TPB - 1) / TPB;   // 119
constexpr int CAP   = 1024;        // LDS sort capacity per (b, class)
constexpr int CAPB  = 768;         // global bucket capacity (mean 434, sigma 20.5)
constexpr int NWORD = 4;           // 256 bits >= 200 for NMS bitmask
constexpr int NBIN  = 2048;        // histogram bins for final top-k select
constexpr unsigned BINBASE = 0x3D000000u;  // 0.03125f — below any score > 0.05
}

#define SCORE_TH 0.05f
#define IOU_TH   0.5f

__device__ __forceinline__ void gload_lds16(const float* g, float* l) {
    __builtin_amdgcn_global_load_lds(
        (const __attribute__((address_space(1))) unsigned int*)g,
        (__attribute__((address_space(3))) unsigned int*)l, 16, 0, 0);
}
__device__ __forceinline__ void gload_lds4(const float* g, float* l) {
    __builtin_amdgcn_global_load_lds(
        (const __attribute__((address_space(1))) unsigned int*)g,
        (__attribute__((address_space(3))) unsigned int*)l, 4, 0, 0);
}

// Descending bitonic sort of P (power of 2) u64 keys in LDS.
// Key = (float_bits(score) << 32) | (0xFFFFFFFF - index)
// => order: score desc, then index asc (matches jax.lax.top_k stability).
__device__ __forceinline__ void bitonic_desc(unsigned long long* keys, int P,
                                             int tid, int nthr) {
    for (int k = 2; k <= P; k <<= 1) {
        for (int j = k >> 1; j > 0; j >>= 1) {
            for (int i = tid; i < P; i += nthr) {
                int ixj = i ^ j;
                if (ixj > i) {
                    unsigned long long a = keys[i], c = keys[ixj];
                    bool up = ((i & k) == 0);
                    if (up ? (a < c) : (a > c)) { keys[i] = c; keys[ixj] = a; }
                }
            }
            __syncthreads();
        }
    }
}

__device__ __forceinline__ float iou_f(float al, float at, float ar, float ab,
                                       float bl, float bt, float br, float bb) {
#pragma clang fp contract(off)
    float l = fmaxf(al, bl);
    float t = fmaxf(at, bt);
    float r = fminf(ar, br);
    float d = fminf(ab, bb);
    float w = fmaxf(r - l, 0.f);
    float h = fmaxf(d - t, 0.f);
    float inter = w * h;
    float areaa = (ar - al) * (ab - at);
    float areab = (br - bl) * (bb - bt);
    return inter / (areaa + areab - inter + 1e-12f);
}

// Kernel 0: zero the per-(b,class) bucket counters.
__global__ __launch_bounds__(256) void ssd_zero_cnt(int* __restrict__ cntg) {
    int i = blockIdx.x * 256 + threadIdx.x;
    if (i < BATCH * C1) cntg[i] = 0;
}

// Kernel 1: stage a [81][128] plabel tile in LDS (single HBM pass), decode
// boxes, exact 2-pass softmax from LDS, push p>TH candidates into buckets.
__global__ __launch_bounds__(128) void ssd_decode_stats(
    const float* __restrict__ ploc, const float* __restrict__ plabel,
    const float* __restrict__ dboxes,
    float* __restrict__ ltrb, float* __restrict__ rowmax,
    float* __restrict__ rowsum,
    int* __restrict__ cntg, unsigned long long* __restrict__ bucket) {
#pragma clang fp contract(off)
    __shared__ float tile[NCLS * TPB];   // 41472 B

    const int tid = threadIdx.x;
    const int b   = blockIdx.x / NBLK;
    const int tb  = blockIdx.x % NBLK;
    const int n0  = tb * TPB;
    const int rem = min(TPB, NANCH - n0);
    const float* pbase = plabel + (size_t)b * NCLS * NANCH;

    if (rem == TPB) {
        // Fast staging: width-16 global_load_lds, 2 rows (256 floats = 1KB)
        // per wave-call. Lane l covers row c0+(l>>5), 16B chunk (l&31).
        // HW writes LDS at (uniform base) + lane*16 — rows contiguous in tile.
        const int wid = tid >> 6, l = tid & 63;
        const int rsel = l >> 5, col = l & 31;
        for (int p = wid; p < 40; p += 2) {
            int c0 = 2 * p;
            const float* src =
                pbase + (size_t)(c0 + rsel) * NANCH + n0 + col * 4;
            gload_lds16(src, &tile[c0 * TPB]);
        }
        // row 80: two half-row width-4 calls (one per wave).
        {
            const float* src = pbase + (size_t)80 * NANCH + n0 + wid * 64 + l;
            gload_lds4(src, &tile[80 * TPB + wid * 64]);
        }
    } else {
        // Tail block (26 anchors): safe scalar staging with clamped columns.
        int n = n0 + tid; if (n >= NANCH) n = NANCH - 1;
        for (int c = 0; c < NCLS; ++c)
            tile[c * TPB + tid] = pbase[(size_t)c * NANCH + n];
    }

    // Decode boxes while staging is in flight (no tile access).
    if (tid < rem) {
        int n = n0 + tid;
        const float* pl = ploc + (size_t)b * 4 * NANCH + n;
        float px = pl[0], py = pl[NANCH], pw = pl[2 * NANCH],
              ph = pl[3 * NANCH];
        float4 db = reinterpret_cast<const float4*>(dboxes)[n];
        float cx = px * 0.1f * db.z + db.x;
        float cy = py * 0.1f * db.w + db.y;
        float w  = expf(pw * 0.2f) * db.z;
        float h  = expf(ph * 0.2f) * db.w;
        float4 o;
        o.x = cx - 0.5f * w; o.y = cy - 0.5f * h;
        o.z = cx + 0.5f * w; o.w = cy + 0.5f * h;
        reinterpret_cast<float4*>(ltrb)[(size_t)b * NANCH + n] = o;
    }

    __syncthreads();   // drains global_load_lds (vmcnt) + joins staging

    if (tid >= rem) return;
    const int n = n0 + tid;

    // Exact 2-pass softmax, same op order as reference (c = 0..80).
    float m = -INFINITY;
    for (int c = 0; c < NCLS; ++c) m = fmaxf(m, tile[c * TPB + tid]);
    float s = 0.f;
    for (int c = 0; c < NCLS; ++c) {
        float e = expf(tile[c * TPB + tid] - m);
        s += e;
        tile[c * TPB + tid] = e;    // reuse tile: store exp for push pass
    }
    rowmax[(size_t)b * NANCH + n] = m;
    rowsum[(size_t)b * NANCH + n] = s;

    // Push pass: p = e / s (bit-identical to expf(x-m)/s).
    for (int c = 1; c < NCLS; ++c) {
        float p = tile[c * TPB + tid] / s;
        if (p > SCORE_TH) {
            int bc = b * C1 + (c - 1);
            int pos = atomicAdd(&cntg[bc], 1);   // wave-uniform address
            if (pos < CAPB)
                bucket[(size_t)bc * CAPB + pos] =
                    ((unsigned long long)__float_as_uint(p) << 32)
                    | (unsigned long long)(0xFFFFFFFFu - (unsigned)n);
        }
    }
}

// Kernel 2: per (b, class): exact top-200 of its bucket + greedy NMS (bitmask).
__global__ __launch_bounds__(256) void ssd_class_nms(
    const float* __restrict__ plabel, const float* __restrict__ rowmax,
    const float* __restrict__ rowsum, const float* __restrict__ ltrb,
    const int* __restrict__ cntg, const unsigned long long* __restrict__ bucket,
    float* __restrict__ pcVals, float* __restrict__ pcBoxes) {
    __shared__ unsigned long long keys[CAP];
    __shared__ float bxl[MAXO], bxt[MAXO], bxr[MAXO], bxb[MAXO], vs[MAXO];
    __shared__ unsigned long long sup[MAXO][NWORD];
    __shared__ unsigned long long keepw[NWORD];
    __shared__ int scanbuf[256];
    __shared__ int cnt, fillcnt;

    const int tid = threadIdx.x;
    const int b   = blockIdx.x / C1;
    const int cls = blockIdx.x % C1 + 1;   // skip background
    const int bc  = b * C1 + (cls - 1);

    if (tid == 0) { cnt = 0; fillcnt = 0; }
    __syncthreads();

    const float* pl = plabel + ((size_t)b * NCLS + cls) * NANCH;
    const float* rm = rowmax + (size_t)b * NANCH;
    const float* rs = rowsum + (size_t)b * NANCH;

    const int gcount = cntg[bc];
    int count;
    if (gcount <= CAPB) {
        for (int i = tid; i < gcount; i += 256)
            keys[i] = bucket[(size_t)bc * CAPB + i];
        count = gcount;
        __syncthreads();
    } else {
        // Overflow fallback (dead in practice): full rescan.
        for (int n = tid; n < NANCH; n += 256) {
            float p = expf(pl[n] - rm[n]) / rs[n];
            if (p > SCORE_TH) {
                int pos = atomicAdd(&cnt, 1);
                if (pos < CAP)
                    keys[pos] = ((unsigned long long)__float_as_uint(p) << 32)
                              | (unsigned long long)(0xFFFFFFFFu - (unsigned)n);
            }
        }
        __syncthreads();
        count = min(cnt, CAP);
    }

    int P = 256; while (P < count) P <<= 1;
    for (int i = count + tid; i < P; i += 256) keys[i] = 0ull;
    __syncthreads();
    bitonic_desc(keys, P, tid, 256);

    // If fewer than 200 positives, fill with smallest anchor indices having
    // prob <= TH (replicates top_k tie-breaking among zeros). Dead in practice.
    if (count < MAXO) {
        const int need = MAXO - count;
        for (int base = 0; base < NANCH; base += 256) {
            if (fillcnt >= need) break;   // uniform (LDS, synced)
            int n = base + tid;
            int flag = 0;
            if (n < NANCH) {
                float p = expf(pl[n] - rm[n]) / rs[n];
                flag = (p <= SCORE_TH) ? 1 : 0;
            }
            scanbuf[tid] = flag;
            __syncthreads();
            for (int off = 1; off < 256; off <<= 1) {
                int v  = scanbuf[tid];
                int vp = (tid >= off) ? scanbuf[tid - off] : 0;
                __syncthreads();
                scanbuf[tid] = v + vp;
                __syncthreads();
            }
            int excl = scanbuf[tid] - flag;
            if (flag && (fillcnt + excl) < need)
                keys[count + fillcnt + excl] =
                    (unsigned long long)(0xFFFFFFFFu - (unsigned)n);
            __syncthreads();
            if (tid == 0) fillcnt += scanbuf[255];
            __syncthreads();
        }
        __syncthreads();
    }

    // Gather top-200 boxes/scores into LDS
    for (int t = tid; t < MAXO; t += 256) {
        unsigned long long key = keys[t];
        float sc   = __uint_as_float((unsigned)(key >> 32));
        unsigned n = 0xFFFFFFFFu - (unsigned)(key & 0xFFFFFFFFull);
        const float4 bb =
            reinterpret_cast<const float4*>(ltrb)[(size_t)b * NANCH + n];
        bxl[t] = bb.x; bxt[t] = bb.y; bxr[t] = bb.z; bxb[t] = bb.w;
        vs[t] = sc;
    }
    __syncthreads();

    // Parallel suppression bit-matrix: sup[i] bit j set iff j>i && IoU>=TH.
    for (int task = tid; task < MAXO * NWORD; task += 256) {
        int i = task >> 2;
        int w = task & (NWORD - 1);
        unsigned long long m = 0ull;
        int jbase = w * 64;
        if (jbase + 63 > i) {
            float al = bxl[i], at = bxt[i], ar = bxr[i], ab = bxb[i];
            int j0 = (jbase > i + 1) ? jbase : i + 1;
            int j1 = (jbase + 64 < MAXO) ? jbase + 64 : MAXO;
            for (int j = j0; j < j1; ++j) {
                float iou = iou_f(al, at, ar, ab,
                                  bxl[j], bxt[j], bxr[j], bxb[j]);
                if (iou >= IOU_TH) m |= 1ull << (j - jbase);
            }
        }
        sup[i][w] = m;
    }
    __syncthreads();

    // Serial greedy propagation (exactly the reference fori_loop recurrence).
    if (tid == 0) {
        unsigned long long k0 = ~0ull, k1 = ~0ull, k2 = ~0ull, k3 = ~0ull;
        for (int i = 0; i < MAXO; ++i) {
            unsigned long long kw = (i < 64) ? k0 : (i < 128) ? k1
                                  : (i < 192) ? k2 : k3;
            if (((kw >> (i & 63)) & 1ull) && vs[i] > 0.f) {
                k0 &= ~sup[i][0]; k1 &= ~sup[i][1];
                k2 &= ~sup[i][2]; k3 &= ~sup[i][3];
            }
        }
        keepw[0] = k0; keepw[1] = k1; keepw[2] = k2; keepw[3] = k3;
    }
    __syncthreads();

    float* pv  = pcVals  + (size_t)bc * MAXO;
    float* pbx = pcBoxes + (size_t)bc * MAXO * 4;
    for (int t = tid; t < MAXO; t += 256) {
        bool kp = (keepw[t >> 6] >> (t & 63)) & 1ull;
        pv[t] = (kp && vs[t] > 0.f) ? vs[t] : 0.f;
        pbx[t * 4 + 0] = bxl[t];
        pbx[t * 4 + 1] = bxt[t];
        pbx[t * 4 + 2] = bxr[t];
        pbx[t * 4 + 3] = bxb[t];
    }
}

// Kernel 3: per image, exact top-200 over the 80*200 flat list via
// histogram cutoff selection + small exact sort.
__global__ __launch_bounds__(256) void ssd_final_topk(
    const float* __restrict__ pcVals, const float* __restrict__ pcBoxes,
    float* __restrict__ out) {
    __shared__ unsigned int hist[NBIN];
    __shared__ int part[256];
    __shared__ unsigned long long cand[CAP];
    __shared__ int cnt, cutbin, nztot;

    const int tid = threadIdx.x;
    const int b   = blockIdx.x;
    const int TOT = C1 * MAXO;   // 16000
    const float* pv = pcVals + (size_t)b * TOT;

    for (int i = tid; i < NBIN; i += 256) hist[i] = 0u;
    if (tid == 0) { cnt = 0; cutbin = 1; }
    __syncthreads();

    for (int g = tid; g < TOT; g += 256) {
        float v = pv[g];
        if (v > 0.f) {
            unsigned bits = __float_as_uint(v);
            unsigned bin = ((bits - BINBASE) >> 15) + 1u;
            if (bin > NBIN - 1) bin = NBIN - 1;
            atomicAdd(&hist[bin], 1u);
        }
    }
    __syncthreads();

    int base = tid * 8;
    int loc = 0;
    for (int k = 0; k < 8; ++k) loc += (int)hist[base + k];
    part[tid] = loc;
    __syncthreads();
    for (int off = 1; off < 256; off <<= 1) {
        int v   = part[tid];
        int add = (tid + off < 256) ? part[tid + off] : 0;
        __syncthreads();
        part[tid] = v + add;
        __syncthreads();
    }
    if (tid == 0) nztot = part[0];
    {
        int suf = (tid + 1 < 256) ? part[tid + 1] : 0;
        int S = suf;
        for (int k = 7; k >= 0; --k) {
            int binv = (int)hist[base + k];
            int Sk = S + binv;
            int bin = base + k;
            if (bin >= 1 && Sk >= MAXO && S < MAXO) cutbin = bin;
            S = Sk;
        }
    }
    __syncthreads();
    int B = (nztot >= MAXO) ? cutbin : 1;

    for (int g = tid; g < TOT; g += 256) {
        float v = pv[g];
        if (v > 0.f) {
            unsigned bits = __float_as_uint(v);
            unsigned bin = ((bits - BINBASE) >> 15) + 1u;
            if (bin > NBIN - 1) bin = NBIN - 1;
            if ((int)bin >= B) {
                int pos = atomicAdd(&cnt, 1);
                if (pos < CAP)
                    cand[pos] = ((unsigned long long)bits << 32)
                              | (unsigned long long)(0xFFFFFFFFu - (unsigned)g);
            }
        }
    }
    __syncthreads();
    int count = min(cnt, CAP);

    if (count < MAXO) {   // dead path
        if (tid == 0) {
            int c = count;
            for (int g = 0; g < TOT && c < MAXO; ++g) {
                if (!(pv[g] > 0.f)) {
                    cand[c++] = (unsigned long long)(0xFFFFFFFFu - (unsigned)g);
                }
            }
            cnt = c;
        }
        __syncthreads();
        count = min(cnt, CAP);
    }

    int P = 256; while (P < count) P <<= 1;
    for (int i = count + tid; i < P; i += 256) cand[i] = 0ull;
    __syncthreads();
    bitonic_desc(cand, P, tid, 256);

    for (int t = tid; t < MAXO; t += 256) {
        unsigned long long key = cand[t];
        float sc      = __uint_as_float((unsigned)(key >> 32));
        unsigned flat = 0xFFFFFFFFu - (unsigned)(key & 0xFFFFFFFFull);
        int cls = (int)(flat / MAXO) + 1;
        const float4 bb =
            reinterpret_cast<const float4*>(pcBoxes)[(size_t)b * TOT + flat];
        reinterpret_cast<float4*>(out)[(size_t)b * MAXO + t] = bb;
        out[(size_t)BATCH * MAXO * 4 + (size_t)b * MAXO + t] = (float)cls;
        out[(size_t)BATCH * MAXO * 5 + (size_t)b * MAXO + t] = sc;
    }
}

extern "C" void kernel_launch(void* const* d_in, const int* in_sizes, int n_in,
                              void* d_out, int out_size, void* d_ws,
                              size_t ws_size, hipStream_t stream) {
    const float* ploc   = (const float*)d_in[0];
    const float* plabel = (const float*)d_in[1];
    const float* dboxes = (const float*)d_in[2];
    float* out = (float*)d_out;

    float* ws      = (float*)d_ws;
    float* ltrb    = ws;                                   // B*N*4
    float* rowmax  = ltrb   + (size_t)BATCH * NANCH * 4;   // B*N
    float* rowsum  = rowmax + (size_t)BATCH * NANCH;       // B*N
    float* pcVals  = rowsum + (size_t)BATCH * NANCH;       // B*80*200
    float* pcBoxes = pcVals + (size_t)BATCH * C1 * MAXO;   // B*80*200*4
    int*   cntg    = (int*)(pcBoxes + (size_t)BATCH * C1 * MAXO * 4);
    unsigned long long* bucket =
        (unsigned long long*)(((char*)(cntg + BATCH * C1)) +
                              ((16 - (((size_t)(cntg + BATCH * C1)) & 15)) & 15));

    ssd_zero_cnt<<<(BATCH * C1 + 255) / 256, 256, 0, stream>>>(cntg);
    ssd_decode_stats<<<BATCH * NBLK, TPB, 0, stream>>>(
        ploc, plabel, dboxes, ltrb, rowmax, rowsum, cntg, bucket);
    ssd_class_nms<<<BATCH * C1, 256, 0, stream>>>(
        plabel, rowmax, rowsum, ltrb, cntg, bucket, pcVals, pcBoxes);
    ssd_final_topk<<<BATCH, 256, 0, stream>>>(pcVals, pcBoxes, out);
}

// Round 5
// 366.288 us; speedup vs baseline: 1.8842x; 1.7204x over previous
//
#include <hip/hip_runtime.h>
#include <math.h>

namespace {
constexpr int BATCH = 32;
constexpr int NANCH = 15130;
constexpr int NCLS  = 81;
constexpr int C1    = 80;          // foreground classes
constexpr int MAXO  = 200;
constexpr int TPB   = 128;         // anchors per K1 block (= threads)
constexpr int NBLK  = (NANCH + TPB - 1) / TPB;   // 119
constexpr int CAP   = 1024;        // LDS sort capacity per (b, class)
constexpr int CAPB  = 768;         // global bucket capacity (mean 434, sigma 20.5)
constexpr int NWORD = 4;           // 256 bits >= 200 for NMS bitmask
constexpr int NBIN  = 2048;        // histogram bins for final top-k select
constexpr unsigned BINBASE = 0x3D000000u;  // 0.03125f — below any score > 0.05
}

#define SCORE_TH 0.05f
#define IOU_TH   0.5f

__device__ __forceinline__ void gload_lds16(const float* g, float* l) {
    __builtin_amdgcn_global_load_lds(
        (const __attribute__((address_space(1))) unsigned int*)g,
        (__attribute__((address_space(3))) unsigned int*)l, 16, 0, 0);
}
__device__ __forceinline__ void gload_lds4(const float* g, float* l) {
    __builtin_amdgcn_global_load_lds(
        (const __attribute__((address_space(1))) unsigned int*)g,
        (__attribute__((address_space(3))) unsigned int*)l, 4, 0, 0);
}

// Descending bitonic sort of P (power of 2) u64 keys in LDS.
// Key = (float_bits(score) << 32) | (0xFFFFFFFF - index)
// => order: score desc, then index asc (matches jax.lax.top_k stability).
// Comparison network => output independent of input permutation (keys distinct).
__device__ __forceinline__ void bitonic_desc(unsigned long long* keys, int P,
                                             int tid, int nthr) {
    for (int k = 2; k <= P; k <<= 1) {
        for (int j = k >> 1; j > 0; j >>= 1) {
            for (int i = tid; i < P; i += nthr) {
                int ixj = i ^ j;
                if (ixj > i) {
                    unsigned long long a = keys[i], c = keys[ixj];
                    bool up = ((i & k) == 0);
                    if (up ? (a < c) : (a > c)) { keys[i] = c; keys[ixj] = a; }
                }
            }
            __syncthreads();
        }
    }
}

__device__ __forceinline__ float iou_f(float al, float at, float ar, float ab,
                                       float bl, float bt, float br, float bb) {
#pragma clang fp contract(off)
    float l = fmaxf(al, bl);
    float t = fmaxf(at, bt);
    float r = fminf(ar, br);
    float d = fminf(ab, bb);
    float w = fmaxf(r - l, 0.f);
    float h = fmaxf(d - t, 0.f);
    float inter = w * h;
    float areaa = (ar - al) * (ab - at);
    float areab = (br - bl) * (bb - bt);
    return inter / (areaa + areab - inter + 1e-12f);
}

// Kernel 0: zero the per-(b,class) bucket counters.
__global__ __launch_bounds__(256) void ssd_zero_cnt(int* __restrict__ cntg) {
    int i = blockIdx.x * 256 + threadIdx.x;
    if (i < BATCH * C1) cntg[i] = 0;
}

// Kernel 1: stage a [81][128] plabel tile in LDS (single HBM pass), decode
// boxes, exact 2-pass softmax from LDS, push p>TH candidates into buckets.
// Bucket push uses LDS count -> one parallel global reservation -> scatter,
// avoiding serialized dependent global atomics (round-4 bottleneck).
__global__ __launch_bounds__(128) void ssd_decode_stats(
    const float* __restrict__ ploc, const float* __restrict__ plabel,
    const float* __restrict__ dboxes,
    float* __restrict__ ltrb, float* __restrict__ rowmax,
    float* __restrict__ rowsum,
    int* __restrict__ cntg, unsigned long long* __restrict__ bucket) {
#pragma clang fp contract(off)
    __shared__ float tile[NCLS * TPB];   // 41472 B
    __shared__ int lcnt[C1], lbase[C1], lrank[C1];

    const int tid = threadIdx.x;
    const int b   = blockIdx.x / NBLK;
    const int tb  = blockIdx.x % NBLK;
    const int n0  = tb * TPB;
    const int rem = min(TPB, NANCH - n0);
    const float* pbase = plabel + (size_t)b * NCLS * NANCH;

    if (rem == TPB) {
        // Fast staging: width-16 global_load_lds, 2 rows (256 floats = 1KB)
        // per wave-call. Lane l covers row c0+(l>>5), 16B chunk (l&31).
        // HW writes LDS at (uniform base) + lane*16 — rows contiguous in tile.
        const int wid = tid >> 6, l = tid & 63;
        const int rsel = l >> 5, col = l & 31;
        for (int p = wid; p < 40; p += 2) {
            int c0 = 2 * p;
            const float* src =
                pbase + (size_t)(c0 + rsel) * NANCH + n0 + col * 4;
            gload_lds16(src, &tile[c0 * TPB]);
        }
        // row 80: two half-row width-4 calls (one per wave).
        {
            const float* src = pbase + (size_t)80 * NANCH + n0 + wid * 64 + l;
            gload_lds4(src, &tile[80 * TPB + wid * 64]);
        }
    } else {
        // Tail block (26 anchors): safe scalar staging with clamped columns.
        int n = n0 + tid; if (n >= NANCH) n = NANCH - 1;
        for (int c = 0; c < NCLS; ++c)
            tile[c * TPB + tid] = pbase[(size_t)c * NANCH + n];
    }

    // Decode boxes while staging is in flight (no tile access).
    if (tid < rem) {
        int n = n0 + tid;
        const float* pl = ploc + (size_t)b * 4 * NANCH + n;
        float px = pl[0], py = pl[NANCH], pw = pl[2 * NANCH],
              ph = pl[3 * NANCH];
        float4 db = reinterpret_cast<const float4*>(dboxes)[n];
        float cx = px * 0.1f * db.z + db.x;
        float cy = py * 0.1f * db.w + db.y;
        float w  = expf(pw * 0.2f) * db.z;
        float h  = expf(ph * 0.2f) * db.w;
        float4 o;
        o.x = cx - 0.5f * w; o.y = cy - 0.5f * h;
        o.z = cx + 0.5f * w; o.w = cy + 0.5f * h;
        reinterpret_cast<float4*>(ltrb)[(size_t)b * NANCH + n] = o;
    }
    if (tid < C1) lcnt[tid] = 0;

    __syncthreads();   // drains global_load_lds (vmcnt) + joins staging

    const int n = n0 + tid;
    float s = 1.f;
    if (tid < rem) {
        // Exact 2-pass softmax, same op order as reference (c = 0..80).
        float m = -INFINITY;
        for (int c = 0; c < NCLS; ++c) m = fmaxf(m, tile[c * TPB + tid]);
        s = 0.f;
        for (int c = 0; c < NCLS; ++c) {
            float e = expf(tile[c * TPB + tid] - m);
            s += e;
            tile[c * TPB + tid] = e;    // reuse tile: store exp
        }
        rowmax[(size_t)b * NANCH + n] = m;
        rowsum[(size_t)b * NANCH + n] = s;

        // Pass A: p = e / s (bit-identical to expf(x-m)/s); store p; LDS count.
        for (int c = 1; c < NCLS; ++c) {
            float p = tile[c * TPB + tid] / s;
            tile[c * TPB + tid] = p;
            if (p > SCORE_TH) atomicAdd(&lcnt[c - 1], 1);
        }
    }
    __syncthreads();

    // One parallel global reservation per class (80 independent lane-atomics).
    if (tid < C1) {
        int cn = lcnt[tid];
        lbase[tid] = (cn > 0) ? atomicAdd(&cntg[b * C1 + tid], cn) : 0;
        lrank[tid] = 0;
    }
    __syncthreads();

    // Pass B: scatter candidates into reserved slots.
    if (tid < rem) {
        for (int c = 1; c < NCLS; ++c) {
            float p = tile[c * TPB + tid];
            if (p > SCORE_TH) {
                int r = atomicAdd(&lrank[c - 1], 1);
                int pos = lbase[c - 1] + r;
                if (pos < CAPB)
                    bucket[(size_t)(b * C1 + (c - 1)) * CAPB + pos] =
                        ((unsigned long long)__float_as_uint(p) << 32)
                        | (unsigned long long)(0xFFFFFFFFu - (unsigned)n);
            }
        }
    }
}

// Kernel 2: per (b, class): exact top-200 of its bucket + greedy NMS (bitmask).
__global__ __launch_bounds__(256) void ssd_class_nms(
    const float* __restrict__ plabel, const float* __restrict__ rowmax,
    const float* __restrict__ rowsum, const float* __restrict__ ltrb,
    const int* __restrict__ cntg, const unsigned long long* __restrict__ bucket,
    float* __restrict__ pcVals, float* __restrict__ pcBoxes) {
    __shared__ unsigned long long keys[CAP];
    __shared__ float bxl[MAXO], bxt[MAXO], bxr[MAXO], bxb[MAXO], vs[MAXO];
    __shared__ unsigned long long sup[MAXO][NWORD];
    __shared__ unsigned long long keepw[NWORD];
    __shared__ int scanbuf[256];
    __shared__ int cnt, fillcnt;

    const int tid = threadIdx.x;
    const int b   = blockIdx.x / C1;
    const int cls = blockIdx.x % C1 + 1;   // skip background
    const int bc  = b * C1 + (cls - 1);

    if (tid == 0) { cnt = 0; fillcnt = 0; }
    __syncthreads();

    const float* pl = plabel + ((size_t)b * NCLS + cls) * NANCH;
    const float* rm = rowmax + (size_t)b * NANCH;
    const float* rs = rowsum + (size_t)b * NANCH;

    const int gcount = cntg[bc];
    int count;
    if (gcount <= CAPB) {
        for (int i = tid; i < gcount; i += 256)
            keys[i] = bucket[(size_t)bc * CAPB + i];
        count = gcount;
        __syncthreads();
    } else {
        // Overflow fallback (dead in practice): full rescan.
        for (int n = tid; n < NANCH; n += 256) {
            float p = expf(pl[n] - rm[n]) / rs[n];
            if (p > SCORE_TH) {
                int pos = atomicAdd(&cnt, 1);
                if (pos < CAP)
                    keys[pos] = ((unsigned long long)__float_as_uint(p) << 32)
                              | (unsigned long long)(0xFFFFFFFFu - (unsigned)n);
            }
        }
        __syncthreads();
        count = min(cnt, CAP);
    }

    int P = 256; while (P < count) P <<= 1;
    for (int i = count + tid; i < P; i += 256) keys[i] = 0ull;
    __syncthreads();
    bitonic_desc(keys, P, tid, 256);

    // If fewer than 200 positives, fill with smallest anchor indices having
    // prob <= TH (replicates top_k tie-breaking among zeros). Dead in practice.
    if (count < MAXO) {
        const int need = MAXO - count;
        for (int base = 0; base < NANCH; base += 256) {
            if (fillcnt >= need) break;   // uniform (LDS, synced)
            int n = base + tid;
            int flag = 0;
            if (n < NANCH) {
                float p = expf(pl[n] - rm[n]) / rs[n];
                flag = (p <= SCORE_TH) ? 1 : 0;
            }
            scanbuf[tid] = flag;
            __syncthreads();
            for (int off = 1; off < 256; off <<= 1) {
                int v  = scanbuf[tid];
                int vp = (tid >= off) ? scanbuf[tid - off] : 0;
                __syncthreads();
                scanbuf[tid] = v + vp;
                __syncthreads();
            }
            int excl = scanbuf[tid] - flag;
            if (flag && (fillcnt + excl) < need)
                keys[count + fillcnt + excl] =
                    (unsigned long long)(0xFFFFFFFFu - (unsigned)n);
            __syncthreads();
            if (tid == 0) fillcnt += scanbuf[255];
            __syncthreads();
        }
        __syncthreads();
    }

    // Gather top-200 boxes/scores into LDS
    for (int t = tid; t < MAXO; t += 256) {
        unsigned long long key = keys[t];
        float sc   = __uint_as_float((unsigned)(key >> 32));
        unsigned n = 0xFFFFFFFFu - (unsigned)(key & 0xFFFFFFFFull);
        const float4 bb =
            reinterpret_cast<const float4*>(ltrb)[(size_t)b * NANCH + n];
        bxl[t] = bb.x; bxt[t] = bb.y; bxr[t] = bb.z; bxb[t] = bb.w;
        vs[t] = sc;
    }
    __syncthreads();

    // Parallel suppression bit-matrix: sup[i] bit j set iff j>i && IoU>=TH.
    for (int task = tid; task < MAXO * NWORD; task += 256) {
        int i = task >> 2;
        int w = task & (NWORD - 1);
        unsigned long long m = 0ull;
        int jbase = w * 64;
        if (jbase + 63 > i) {
            float al = bxl[i], at = bxt[i], ar = bxr[i], ab = bxb[i];
            int j0 = (jbase > i + 1) ? jbase : i + 1;
            int j1 = (jbase + 64 < MAXO) ? jbase + 64 : MAXO;
            for (int j = j0; j < j1; ++j) {
                float iou = iou_f(al, at, ar, ab,
                                  bxl[j], bxt[j], bxr[j], bxb[j]);
                if (iou >= IOU_TH) m |= 1ull << (j - jbase);
            }
        }
        sup[i][w] = m;
    }
    __syncthreads();

    // Serial greedy propagation (exactly the reference fori_loop recurrence).
    if (tid == 0) {
        unsigned long long k0 = ~0ull, k1 = ~0ull, k2 = ~0ull, k3 = ~0ull;
        for (int i = 0; i < MAXO; ++i) {
            unsigned long long kw = (i < 64) ? k0 : (i < 128) ? k1
                                  : (i < 192) ? k2 : k3;
            if (((kw >> (i & 63)) & 1ull) && vs[i] > 0.f) {
                k0 &= ~sup[i][0]; k1 &= ~sup[i][1];
                k2 &= ~sup[i][2]; k3 &= ~sup[i][3];
            }
        }
        keepw[0] = k0; keepw[1] = k1; keepw[2] = k2; keepw[3] = k3;
    }
    __syncthreads();

    float* pv  = pcVals  + (size_t)bc * MAXO;
    float* pbx = pcBoxes + (size_t)bc * MAXO * 4;
    for (int t = tid; t < MAXO; t += 256) {
        bool kp = (keepw[t >> 6] >> (t & 63)) & 1ull;
        pv[t] = (kp && vs[t] > 0.f) ? vs[t] : 0.f;
        pbx[t * 4 + 0] = bxl[t];
        pbx[t * 4 + 1] = bxt[t];
        pbx[t * 4 + 2] = bxr[t];
        pbx[t * 4 + 3] = bxb[t];
    }
}

// Kernel 3: per image, exact top-200 over the 80*200 flat list via
// histogram cutoff selection + small exact sort.
__global__ __launch_bounds__(256) void ssd_final_topk(
    const float* __restrict__ pcVals, const float* __restrict__ pcBoxes,
    float* __restrict__ out) {
    __shared__ unsigned int hist[NBIN];
    __shared__ int part[256];
    __shared__ unsigned long long cand[CAP];
    __shared__ int cnt, cutbin, nztot;

    const int tid = threadIdx.x;
    const int b   = blockIdx.x;
    const int TOT = C1 * MAXO;   // 16000
    const float* pv = pcVals + (size_t)b * TOT;

    for (int i = tid; i < NBIN; i += 256) hist[i] = 0u;
    if (tid == 0) { cnt = 0; cutbin = 1; }
    __syncthreads();

    for (int g = tid; g < TOT; g += 256) {
        float v = pv[g];
        if (v > 0.f) {
            unsigned bits = __float_as_uint(v);
            unsigned bin = ((bits - BINBASE) >> 15) + 1u;
            if (bin > NBIN - 1) bin = NBIN - 1;
            atomicAdd(&hist[bin], 1u);
        }
    }
    __syncthreads();

    int base = tid * 8;
    int loc = 0;
    for (int k = 0; k < 8; ++k) loc += (int)hist[base + k];
    part[tid] = loc;
    __syncthreads();
    for (int off = 1; off < 256; off <<= 1) {
        int v   = part[tid];
        int add = (tid + off < 256) ? part[tid + off] : 0;
        __syncthreads();
        part[tid] = v + add;
        __syncthreads();
    }
    if (tid == 0) nztot = part[0];
    {
        int suf = (tid + 1 < 256) ? part[tid + 1] : 0;
        int S = suf;
        for (int k = 7; k >= 0; --k) {
            int binv = (int)hist[base + k];
            int Sk = S + binv;
            int bin = base + k;
            if (bin >= 1 && Sk >= MAXO && S < MAXO) cutbin = bin;
            S = Sk;
        }
    }
    __syncthreads();
    int B = (nztot >= MAXO) ? cutbin : 1;

    for (int g = tid; g < TOT; g += 256) {
        float v = pv[g];
        if (v > 0.f) {
            unsigned bits = __float_as_uint(v);
            unsigned bin = ((bits - BINBASE) >> 15) + 1u;
            if (bin > NBIN - 1) bin = NBIN - 1;
            if ((int)bin >= B) {
                int pos = atomicAdd(&cnt, 1);
                if (pos < CAP)
                    cand[pos] = ((unsigned long long)bits << 32)
                              | (unsigned long long)(0xFFFFFFFFu - (unsigned)g);
            }
        }
    }
    __syncthreads();
    int count = min(cnt, CAP);

    if (count < MAXO) {   // dead path
        if (tid == 0) {
            int c = count;
            for (int g = 0; g < TOT && c < MAXO; ++g) {
                if (!(pv[g] > 0.f)) {
                    cand[c++] = (unsigned long long)(0xFFFFFFFFu - (unsigned)g);
                }
            }
            cnt = c;
        }
        __syncthreads();
        count = min(cnt, CAP);
    }

    int P = 256; while (P < count) P <<= 1;
    for (int i = count + tid; i < P; i += 256) cand[i] = 0ull;
    __syncthreads();
    bitonic_desc(cand, P, tid, 256);

    for (int t = tid; t < MAXO; t += 256) {
        unsigned long long key = cand[t];
        float sc      = __uint_as_float((unsigned)(key >> 32));
        unsigned flat = 0xFFFFFFFFu - (unsigned)(key & 0xFFFFFFFFull);
        int cls = (int)(flat / MAXO) + 1;
        const float4 bb =
            reinterpret_cast<const float4*>(pcBoxes)[(size_t)b * TOT + flat];
        reinterpret_cast<float4*>(out)[(size_t)b * MAXO + t] = bb;
        out[(size_t)BATCH * MAXO * 4 + (size_t)b * MAXO + t] = (float)cls;
        out[(size_t)BATCH * MAXO * 5 + (size_t)b * MAXO + t] = sc;
    }
}

extern "C" void kernel_launch(void* const* d_in, const int* in_sizes, int n_in,
                              void* d_out, int out_size, void* d_ws,
                              size_t ws_size, hipStream_t stream) {
    const float* ploc   = (const float*)d_in[0];
    const float* plabel = (const float*)d_in[1];
    const float* dboxes = (const float*)d_in[2];
    float* out = (float*)d_out;

    float* ws      = (float*)d_ws;
    float* ltrb    = ws;                                   // B*N*4
    float* rowmax  = ltrb   + (size_t)BATCH * NANCH * 4;   // B*N
    float* rowsum  = rowmax + (size_t)BATCH * NANCH;       // B*N
    float* pcVals  = rowsum + (size_t)BATCH * NANCH;       // B*80*200
    float* pcBoxes = pcVals + (size_t)BATCH * C1 * MAXO;   // B*80*200*4
    int*   cntg    = (int*)(pcBoxes + (size_t)BATCH * C1 * MAXO * 4);
    unsigned long long* bucket =
        (unsigned long long*)(((char*)(cntg + BATCH * C1)) +
                              ((16 - (((size_t)(cntg + BATCH * C1)) & 15)) & 15));

    ssd_zero_cnt<<<(BATCH * C1 + 255) / 256, 256, 0, stream>>>(cntg);
    ssd_decode_stats<<<BATCH * NBLK, TPB, 0, stream>>>(
        ploc, plabel, dboxes, ltrb, rowmax, rowsum, cntg, bucket);
    ssd_class_nms<<<BATCH * C1, 256, 0, stream>>>(
        plabel, rowmax, rowsum, ltrb, cntg, bucket, pcVals, pcBoxes);
    ssd_final_topk<<<BATCH, 256, 0, stream>>>(pcVals, pcBoxes, out);
}

// Round 6
// 343.817 us; speedup vs baseline: 2.0073x; 1.0654x over previous
//
#include <hip/hip_runtime.h>
#include <math.h>

namespace {
constexpr int BATCH = 32;
constexpr int NANCH = 15130;
constexpr int NCLS  = 81;
constexpr int C1    = 80;          // foreground classes
constexpr int MAXO  = 200;
constexpr int TPB   = 128;         // anchors per K1 block (= threads)
constexpr int NBLK  = (NANCH + TPB - 1) / TPB;   // 119
constexpr int CAP   = 1024;        // cand capacity (sort buffer)
constexpr int CAPB  = 768;         // global bucket capacity (mean 434, sigma 20.5)
constexpr int NWORD = 4;           // 256 bits >= 200 for NMS bitmask
constexpr int NBIN  = 2048;        // histogram bins for final top-k select (K3)
constexpr int NBINK2 = 1536;       // histogram bins for K2 select (max used 1281)
constexpr unsigned BINBASE = 0x3D000000u;  // 0.03125f — below any score > 0.05
}

#define SCORE_TH 0.05f
#define IOU_TH   0.5f

__device__ __forceinline__ void gload_lds16(const float* g, float* l) {
    __builtin_amdgcn_global_load_lds(
        (const __attribute__((address_space(1))) unsigned int*)g,
        (__attribute__((address_space(3))) unsigned int*)l, 16, 0, 0);
}
__device__ __forceinline__ void gload_lds4(const float* g, float* l) {
    __builtin_amdgcn_global_load_lds(
        (const __attribute__((address_space(1))) unsigned int*)g,
        (__attribute__((address_space(3))) unsigned int*)l, 4, 0, 0);
}

// Descending bitonic sort of P (power of 2) u64 keys in LDS.
// Key = (float_bits(score) << 32) | (0xFFFFFFFF - index)
// => order: score desc, then index asc (matches jax.lax.top_k stability).
// Comparison network => output independent of input permutation (keys distinct).
__device__ __forceinline__ void bitonic_desc(unsigned long long* keys, int P,
                                             int tid, int nthr) {
    for (int k = 2; k <= P; k <<= 1) {
        for (int j = k >> 1; j > 0; j >>= 1) {
            for (int i = tid; i < P; i += nthr) {
                int ixj = i ^ j;
                if (ixj > i) {
                    unsigned long long a = keys[i], c = keys[ixj];
                    bool up = ((i & k) == 0);
                    if (up ? (a < c) : (a > c)) { keys[i] = c; keys[ixj] = a; }
                }
            }
            __syncthreads();
        }
    }
}

// Kernel 0: zero the per-(b,class) bucket counters.
__global__ __launch_bounds__(256) void ssd_zero_cnt(int* __restrict__ cntg) {
    int i = blockIdx.x * 256 + threadIdx.x;
    if (i < BATCH * C1) cntg[i] = 0;
}

// Kernel 1: stage a [81][128] plabel tile in LDS (single HBM pass), decode
// boxes, exact 2-pass softmax from LDS, push p>TH candidates into buckets.
__global__ __launch_bounds__(128) void ssd_decode_stats(
    const float* __restrict__ ploc, const float* __restrict__ plabel,
    const float* __restrict__ dboxes,
    float* __restrict__ ltrb, float* __restrict__ rowmax,
    float* __restrict__ rowsum,
    int* __restrict__ cntg, unsigned long long* __restrict__ bucket) {
#pragma clang fp contract(off)
    __shared__ float tile[NCLS * TPB];   // 41472 B
    __shared__ int lcnt[C1], lbase[C1], lrank[C1];

    const int tid = threadIdx.x;
    const int b   = blockIdx.x / NBLK;
    const int tb  = blockIdx.x % NBLK;
    const int n0  = tb * TPB;
    const int rem = min(TPB, NANCH - n0);
    const float* pbase = plabel + (size_t)b * NCLS * NANCH;

    if (rem == TPB) {
        const int wid = tid >> 6, l = tid & 63;
        const int rsel = l >> 5, col = l & 31;
        for (int p = wid; p < 40; p += 2) {
            int c0 = 2 * p;
            const float* src =
                pbase + (size_t)(c0 + rsel) * NANCH + n0 + col * 4;
            gload_lds16(src, &tile[c0 * TPB]);
        }
        {
            const float* src = pbase + (size_t)80 * NANCH + n0 + wid * 64 + l;
            gload_lds4(src, &tile[80 * TPB + wid * 64]);
        }
    } else {
        int n = n0 + tid; if (n >= NANCH) n = NANCH - 1;
        for (int c = 0; c < NCLS; ++c)
            tile[c * TPB + tid] = pbase[(size_t)c * NANCH + n];
    }

    // Decode boxes while staging is in flight (no tile access).
    if (tid < rem) {
        int n = n0 + tid;
        const float* pl = ploc + (size_t)b * 4 * NANCH + n;
        float px = pl[0], py = pl[NANCH], pw = pl[2 * NANCH],
              ph = pl[3 * NANCH];
        float4 db = reinterpret_cast<const float4*>(dboxes)[n];
        float cx = px * 0.1f * db.z + db.x;
        float cy = py * 0.1f * db.w + db.y;
        float w  = expf(pw * 0.2f) * db.z;
        float h  = expf(ph * 0.2f) * db.w;
        float4 o;
        o.x = cx - 0.5f * w; o.y = cy - 0.5f * h;
        o.z = cx + 0.5f * w; o.w = cy + 0.5f * h;
        reinterpret_cast<float4*>(ltrb)[(size_t)b * NANCH + n] = o;
    }
    if (tid < C1) lcnt[tid] = 0;

    __syncthreads();

    const int n = n0 + tid;
    float s = 1.f;
    if (tid < rem) {
        float m = -INFINITY;
        for (int c = 0; c < NCLS; ++c) m = fmaxf(m, tile[c * TPB + tid]);
        s = 0.f;
        for (int c = 0; c < NCLS; ++c) {
            float e = expf(tile[c * TPB + tid] - m);
            s += e;
            tile[c * TPB + tid] = e;
        }
        rowmax[(size_t)b * NANCH + n] = m;
        rowsum[(size_t)b * NANCH + n] = s;

        for (int c = 1; c < NCLS; ++c) {
            float p = tile[c * TPB + tid] / s;
            tile[c * TPB + tid] = p;
            if (p > SCORE_TH) atomicAdd(&lcnt[c - 1], 1);
        }
    }
    __syncthreads();

    if (tid < C1) {
        int cn = lcnt[tid];
        lbase[tid] = (cn > 0) ? atomicAdd(&cntg[b * C1 + tid], cn) : 0;
        lrank[tid] = 0;
    }
    __syncthreads();

    if (tid < rem) {
        for (int c = 1; c < NCLS; ++c) {
            float p = tile[c * TPB + tid];
            if (p > SCORE_TH) {
                int r = atomicAdd(&lrank[c - 1], 1);
                int pos = lbase[c - 1] + r;
                if (pos < CAPB)
                    bucket[(size_t)(b * C1 + (c - 1)) * CAPB + pos] =
                        ((unsigned long long)__float_as_uint(p) << 32)
                        | (unsigned long long)(0xFFFFFFFFu - (unsigned)n);
            }
        }
    }
}

// Kernel 2: per (b, class): histogram-select ~top-200, sort P=256, NMS.
__global__ __launch_bounds__(256) void ssd_class_nms(
    const float* __restrict__ plabel, const float* __restrict__ rowmax,
    const float* __restrict__ rowsum, const float* __restrict__ ltrb,
    const int* __restrict__ cntg, const unsigned long long* __restrict__ bucket,
    float* __restrict__ pcVals, float* __restrict__ pcBoxes) {
    __shared__ unsigned long long cand[CAP];          // 8 KB
    __shared__ unsigned int hist[NBINK2];             // 6 KB
    __shared__ int part[256];                         // 1 KB
    __shared__ float4 box4[MAXO];                     // 3.2 KB
    __shared__ float areas[MAXO], vs[MAXO];           // 1.6 KB
    __shared__ unsigned long long sup[MAXO][NWORD];   // 6.4 KB
    __shared__ unsigned long long keepw[NWORD], vmaskS[NWORD];
    __shared__ int cnt, fillcnt, cutbin, nztot;

    const int tid = threadIdx.x;
    const int b   = blockIdx.x / C1;
    const int cls = blockIdx.x % C1 + 1;   // skip background
    const int bc  = b * C1 + (cls - 1);

    for (int i = tid; i < NBINK2; i += 256) hist[i] = 0u;
    if (tid == 0) { cnt = 0; fillcnt = 0; cutbin = 1; }
    __syncthreads();

    const float* pl = plabel + ((size_t)b * NCLS + cls) * NANCH;
    const float* rm = rowmax + (size_t)b * NANCH;
    const float* rs = rowsum + (size_t)b * NANCH;
    const unsigned long long* bkt = bucket + (size_t)bc * CAPB;

    const int gcount = cntg[bc];
    const bool ovf = (gcount > CAPB);   // uniform; dead in practice
    int count, gathered;

    if (!ovf) {
        count = gcount;
        // Pass 1: histogram of bucket scores (bucket stays in L2; re-read later).
        for (int i = tid; i < count; i += 256) {
            unsigned bits = (unsigned)(bkt[i] >> 32);
            unsigned bin = ((bits - BINBASE) >> 15) + 1u;
            if (bin > NBINK2 - 1) bin = NBINK2 - 1;
            atomicAdd(&hist[bin], 1u);
        }
        __syncthreads();

        // Suffix-scan (thread owns 6 bins) -> exact cutoff bin B.
        int base = tid * 6;
        int loc = 0;
        for (int k = 0; k < 6; ++k) loc += (int)hist[base + k];
        part[tid] = loc;
        __syncthreads();
        for (int off = 1; off < 256; off <<= 1) {
            int v   = part[tid];
            int add = (tid + off < 256) ? part[tid + off] : 0;
            __syncthreads();
            part[tid] = v + add;
            __syncthreads();
        }
        if (tid == 0) nztot = part[0];
        {
            int suf = (tid + 1 < 256) ? part[tid + 1] : 0;
            int S = suf;
            for (int k = 5; k >= 0; --k) {
                int binv = (int)hist[base + k];
                int Sk = S + binv;
                int bin = base + k;
                if (bin >= 1 && Sk >= MAXO && S < MAXO) cutbin = bin;
                S = Sk;
            }
        }
        __syncthreads();
        int B = (nztot >= MAXO) ? cutbin : 1;

        // Pass 2: gather keys with bin >= B (top-200 is a subset; ~205 items).
        for (int i = tid; i < count; i += 256) {
            unsigned long long k = bkt[i];
            unsigned bits = (unsigned)(k >> 32);
            unsigned bin = ((bits - BINBASE) >> 15) + 1u;
            if (bin > NBINK2 - 1) bin = NBINK2 - 1;
            if ((int)bin >= B) {
                int pos = atomicAdd(&cnt, 1);
                if (pos < CAP) cand[pos] = k;
            }
        }
        __syncthreads();
        gathered = min(cnt, CAP);
    } else {
        // Overflow fallback (dead): full rescan, no select.
        for (int n = tid; n < NANCH; n += 256) {
            float p = expf(pl[n] - rm[n]) / rs[n];
            if (p > SCORE_TH) {
                int pos = atomicAdd(&cnt, 1);
                if (pos < CAP)
                    cand[pos] = ((unsigned long long)__float_as_uint(p) << 32)
                              | (unsigned long long)(0xFFFFFFFFu - (unsigned)n);
            }
        }
        __syncthreads();
        count = gathered = min(cnt, CAP);
    }

    int P = 256; while (P < gathered) P <<= 1;
    for (int i = gathered + tid; i < P; i += 256) cand[i] = 0ull;
    __syncthreads();
    bitonic_desc(cand, P, tid, 256);

    // If fewer than 200 positives, fill with smallest anchor indices having
    // prob <= TH (replicates top_k tie-breaking among zeros). Dead in practice.
    if (gathered < MAXO) {
        const int need = MAXO - gathered;
        for (int base2 = 0; base2 < NANCH; base2 += 256) {
            if (fillcnt >= need) break;   // uniform (LDS, synced)
            int n = base2 + tid;
            int flag = 0;
            if (n < NANCH) {
                float p = expf(pl[n] - rm[n]) / rs[n];
                flag = (p <= SCORE_TH) ? 1 : 0;
            }
            part[tid] = flag;
            __syncthreads();
            for (int off = 1; off < 256; off <<= 1) {
                int v  = part[tid];
                int vp = (tid >= off) ? part[tid - off] : 0;
                __syncthreads();
                part[tid] = v + vp;
                __syncthreads();
            }
            int excl = part[tid] - flag;
            if (flag && (fillcnt + excl) < need)
                cand[gathered + fillcnt + excl] =
                    (unsigned long long)(0xFFFFFFFFu - (unsigned)n);
            __syncthreads();
            if (tid == 0) fillcnt += part[255];
            __syncthreads();
        }
        __syncthreads();
    }

    // Gather top-200 boxes/scores/areas into LDS (one thread per t).
    if (tid < MAXO) {
#pragma clang fp contract(off)
        unsigned long long key = cand[tid];
        float sc   = __uint_as_float((unsigned)(key >> 32));
        unsigned n = 0xFFFFFFFFu - (unsigned)(key & 0xFFFFFFFFull);
        float4 bb =
            reinterpret_cast<const float4*>(ltrb)[(size_t)b * NANCH + n];
        box4[tid] = bb;
        areas[tid] = (bb.z - bb.x) * (bb.w - bb.y);
        vs[tid] = sc;
    }
    __syncthreads();

    // vs>0 bitmask via per-wave ballot (wave w = word w).
    {
        bool pred = (tid < MAXO) ? (vs[tid] > 0.f) : false;
        unsigned long long bal = __ballot(pred);
        if ((tid & 63) == 0) vmaskS[tid >> 6] = bal;
    }

    // Suppression bit-matrix, one i per thread: bit j set iff j>i && IoU>=TH.
    if (tid < MAXO) {
#pragma clang fp contract(off)
        const int i = tid;
        float4 bi = box4[i];
        float ai = areas[i];
        unsigned long long m0 = 0, m1 = 0, m2 = 0, m3 = 0;
        for (int j = i + 1; j < MAXO; ++j) {
            float4 bj = box4[j];
            float l = fmaxf(bi.x, bj.x);
            float t = fmaxf(bi.y, bj.y);
            float r = fminf(bi.z, bj.z);
            float d = fminf(bi.w, bj.w);
            float w = fmaxf(r - l, 0.f);
            float h = fmaxf(d - t, 0.f);
            float inter = w * h;
            float iou = inter / (ai + areas[j] - inter + 1e-12f);
            if (iou >= IOU_TH) {
                unsigned long long bit = 1ull << (j & 63);
                switch (j >> 6) {
                    case 0: m0 |= bit; break;
                    case 1: m1 |= bit; break;
                    case 2: m2 |= bit; break;
                    default: m3 |= bit; break;
                }
            }
        }
        sup[i][0] = m0; sup[i][1] = m1; sup[i][2] = m2; sup[i][3] = m3;
    }
    __syncthreads();

    // Serial greedy propagation on registers (reference fori_loop recurrence).
    if (tid == 0) {
        unsigned long long v0 = vmaskS[0], v1 = vmaskS[1],
                           v2 = vmaskS[2], v3 = vmaskS[3];
        unsigned long long k0 = ~0ull, k1 = ~0ull, k2 = ~0ull, k3 = ~0ull;
        for (int i = 0; i < MAXO; ++i) {
            unsigned long long kw = (i < 64) ? k0 : (i < 128) ? k1
                                  : (i < 192) ? k2 : k3;
            unsigned long long vw = (i < 64) ? v0 : (i < 128) ? v1
                                  : (i < 192) ? v2 : v3;
            if (((kw & vw) >> (i & 63)) & 1ull) {
                k0 &= ~sup[i][0]; k1 &= ~sup[i][1];
                k2 &= ~sup[i][2]; k3 &= ~sup[i][3];
            }
        }
        keepw[0] = k0; keepw[1] = k1; keepw[2] = k2; keepw[3] = k3;
    }
    __syncthreads();

    if (tid < MAXO) {
        bool kp = (keepw[tid >> 6] >> (tid & 63)) & 1ull;
        pcVals[(size_t)bc * MAXO + tid] = (kp && vs[tid] > 0.f) ? vs[tid] : 0.f;
        reinterpret_cast<float4*>(pcBoxes + (size_t)bc * MAXO * 4)[tid] =
            box4[tid];
    }
}

// Kernel 3: per image, exact top-200 over the 80*200 flat list via
// histogram cutoff selection + small exact sort.
__global__ __launch_bounds__(256) void ssd_final_topk(
    const float* __restrict__ pcVals, const float* __restrict__ pcBoxes,
    float* __restrict__ out) {
    __shared__ unsigned int hist[NBIN];
    __shared__ int part[256];
    __shared__ unsigned long long cand[CAP];
    __shared__ int cnt, cutbin, nztot;

    const int tid = threadIdx.x;
    const int b   = blockIdx.x;
    const int TOT = C1 * MAXO;   // 16000
    const float* pv = pcVals + (size_t)b * TOT;

    for (int i = tid; i < NBIN; i += 256) hist[i] = 0u;
    if (tid == 0) { cnt = 0; cutbin = 1; }
    __syncthreads();

    for (int g = tid; g < TOT; g += 256) {
        float v = pv[g];
        if (v > 0.f) {
            unsigned bits = __float_as_uint(v);
            unsigned bin = ((bits - BINBASE) >> 15) + 1u;
            if (bin > NBIN - 1) bin = NBIN - 1;
            atomicAdd(&hist[bin], 1u);
        }
    }
    __syncthreads();

    int base = tid * 8;
    int loc = 0;
    for (int k = 0; k < 8; ++k) loc += (int)hist[base + k];
    part[tid] = loc;
    __syncthreads();
    for (int off = 1; off < 256; off <<= 1) {
        int v   = part[tid];
        int add = (tid + off < 256) ? part[tid + off] : 0;
        __syncthreads();
        part[tid] = v + add;
        __syncthreads();
    }
    if (tid == 0) nztot = part[0];
    {
        int suf = (tid + 1 < 256) ? part[tid + 1] : 0;
        int S = suf;
        for (int k = 7; k >= 0; --k) {
            int binv = (int)hist[base + k];
            int Sk = S + binv;
            int bin = base + k;
            if (bin >= 1 && Sk >= MAXO && S < MAXO) cutbin = bin;
            S = Sk;
        }
    }
    __syncthreads();
    int B = (nztot >= MAXO) ? cutbin : 1;

    for (int g = tid; g < TOT; g += 256) {
        float v = pv[g];
        if (v > 0.f) {
            unsigned bits = __float_as_uint(v);
            unsigned bin = ((bits - BINBASE) >> 15) + 1u;
            if (bin > NBIN - 1) bin = NBIN - 1;
            if ((int)bin >= B) {
                int pos = atomicAdd(&cnt, 1);
                if (pos < CAP)
                    cand[pos] = ((unsigned long long)bits << 32)
                              | (unsigned long long)(0xFFFFFFFFu - (unsigned)g);
            }
        }
    }
    __syncthreads();
    int count = min(cnt, CAP);

    if (count < MAXO) {   // dead path
        if (tid == 0) {
            int c = count;
            for (int g = 0; g < TOT && c < MAXO; ++g) {
                if (!(pv[g] > 0.f)) {
                    cand[c++] = (unsigned long long)(0xFFFFFFFFu - (unsigned)g);
                }
            }
            cnt = c;
        }
        __syncthreads();
        count = min(cnt, CAP);
    }

    int P = 256; while (P < count) P <<= 1;
    for (int i = count + tid; i < P; i += 256) cand[i] = 0ull;
    __syncthreads();
    bitonic_desc(cand, P, tid, 256);

    for (int t = tid; t < MAXO; t += 256) {
        unsigned long long key = cand[t];
        float sc      = __uint_as_float((unsigned)(key >> 32));
        unsigned flat = 0xFFFFFFFFu - (unsigned)(key & 0xFFFFFFFFull);
        int cls = (int)(flat / MAXO) + 1;
        const float4 bb =
            reinterpret_cast<const float4*>(pcBoxes)[(size_t)b * TOT + flat];
        reinterpret_cast<float4*>(out)[(size_t)b * MAXO + t] = bb;
        out[(size_t)BATCH * MAXO * 4 + (size_t)b * MAXO + t] = (float)cls;
        out[(size_t)BATCH * MAXO * 5 + (size_t)b * MAXO + t] = sc;
    }
}

extern "C" void kernel_launch(void* const* d_in, const int* in_sizes, int n_in,
                              void* d_out, int out_size, void* d_ws,
                              size_t ws_size, hipStream_t stream) {
    const float* ploc   = (const float*)d_in[0];
    const float* plabel = (const float*)d_in[1];
    const float* dboxes = (const float*)d_in[2];
    float* out = (float*)d_out;

    float* ws      = (float*)d_ws;
    float* ltrb    = ws;                                   // B*N*4
    float* rowmax  = ltrb   + (size_t)BATCH * NANCH * 4;   // B*N
    float* rowsum  = rowmax + (size_t)BATCH * NANCH;       // B*N
    float* pcVals  = rowsum + (size_t)BATCH * NANCH;       // B*80*200
    float* pcBoxes = pcVals + (size_t)BATCH * C1 * MAXO;   // B*80*200*4
    int*   cntg    = (int*)(pcBoxes + (size_t)BATCH * C1 * MAXO * 4);
    unsigned long long* bucket =
        (unsigned long long*)(((char*)(cntg + BATCH * C1)) +
                              ((16 - (((size_t)(cntg + BATCH * C1)) & 15)) & 15));

    ssd_zero_cnt<<<(BATCH * C1 + 255) / 256, 256, 0, stream>>>(cntg);
    ssd_decode_stats<<<BATCH * NBLK, TPB, 0, stream>>>(
        ploc, plabel, dboxes, ltrb, rowmax, rowsum, cntg, bucket);
    ssd_class_nms<<<BATCH * C1, 256, 0, stream>>>(
        plabel, rowmax, rowsum, ltrb, cntg, bucket, pcVals, pcBoxes);
    ssd_final_topk<<<BATCH, 256, 0, stream>>>(pcVals, pcBoxes, out);
}

// Round 7
// 264.354 us; speedup vs baseline: 2.6107x; 1.3006x over previous
//
#include <hip/hip_runtime.h>
#include <math.h>

namespace {
constexpr int BATCH = 32;
constexpr int NANCH = 15130;
constexpr int NCLS  = 81;
constexpr int C1    = 80;          // foreground classes
constexpr int MAXO  = 200;
constexpr int APB   = 256;         // anchors per K1 block (= threads)
constexpr int NBLKA = (NANCH + APB - 1) / APB;   // 60
constexpr int CAP   = 1024;        // cand capacity (sort buffer)
constexpr int CAPB  = 768;         // global bucket capacity (mean 434, sigma 20.5)
constexpr int NWORD = 4;           // 256 bits >= 200 for NMS bitmask
constexpr int NBIN  = 2048;        // histogram bins for final top-k select (K3)
constexpr int NBINK2 = 1536;       // histogram bins for K2 select (max used 1281)
constexpr unsigned BINBASE = 0x3D000000u;  // 0.03125f — below any score > 0.05
}

#define SCORE_TH 0.05f
#define IOU_TH   0.5f

// Descending bitonic sort of P (power of 2) u64 keys in LDS.
// Key = (float_bits(score) << 32) | (0xFFFFFFFF - index)
// => order: score desc, then index asc (matches jax.lax.top_k stability).
// Comparison network => output independent of input permutation (keys distinct).
__device__ __forceinline__ void bitonic_desc(unsigned long long* keys, int P,
                                             int tid, int nthr) {
    for (int k = 2; k <= P; k <<= 1) {
        for (int j = k >> 1; j > 0; j >>= 1) {
            for (int i = tid; i < P; i += nthr) {
                int ixj = i ^ j;
                if (ixj > i) {
                    unsigned long long a = keys[i], c = keys[ixj];
                    bool up = ((i & k) == 0);
                    if (up ? (a < c) : (a > c)) { keys[i] = c; keys[ixj] = a; }
                }
            }
            __syncthreads();
        }
    }
}

// Kernel 0: zero the per-(b,class) bucket counters.
__global__ __launch_bounds__(256) void ssd_zero_cnt(int* __restrict__ cntg) {
    int i = blockIdx.x * 256 + threadIdx.x;
    if (i < BATCH * C1) cntg[i] = 0;
}

// Kernel 1: one thread per anchor. 81 class logits live in REGISTERS
// (fully unrolled static-index loads -> VGPRs, coalesced 256B/wave).
// Register softmax (exact reference op order), decode, then the proven
// LDS-count -> one-global-reservation -> scatter bucket push.
__global__ __launch_bounds__(256) void ssd_decode_stats(
    const float* __restrict__ ploc, const float* __restrict__ plabel,
    const float* __restrict__ dboxes,
    float* __restrict__ ltrb, float* __restrict__ rowmax,
    float* __restrict__ rowsum,
    int* __restrict__ cntg, unsigned long long* __restrict__ bucket) {
#pragma clang fp contract(off)
    __shared__ int lcnt[C1], lbase[C1], lrank[C1];

    const int tid = threadIdx.x;
    const int b   = blockIdx.x / NBLKA;
    const int n0  = (blockIdx.x % NBLKA) * APB;
    const int n   = n0 + tid;
    const bool act = (n < NANCH);

    if (tid < C1) lcnt[tid] = 0;

    float x[NCLS];
    if (act) {
        // ---- decode box ----
        const float* pl = ploc + (size_t)b * 4 * NANCH + n;
        float px = pl[0], py = pl[NANCH], pw = pl[2 * NANCH],
              ph = pl[3 * NANCH];
        float4 db = reinterpret_cast<const float4*>(dboxes)[n];
        float cx = px * 0.1f * db.z + db.x;
        float cy = py * 0.1f * db.w + db.y;
        float w  = expf(pw * 0.2f) * db.z;
        float h  = expf(ph * 0.2f) * db.w;
        float4 o;
        o.x = cx - 0.5f * w; o.y = cy - 0.5f * h;
        o.z = cx + 0.5f * w; o.w = cy + 0.5f * h;
        reinterpret_cast<float4*>(ltrb)[(size_t)b * NANCH + n] = o;

        // ---- load 81 logits into registers (independent coalesced loads) ----
        const float* pb = plabel + (size_t)b * NCLS * NANCH + n;
#pragma unroll
        for (int c = 0; c < NCLS; ++c) x[c] = pb[(size_t)c * NANCH];

        // ---- softmax: max (exact for any order), then e, then ORDERED sum ----
        float m = -INFINITY;
#pragma unroll
        for (int c = 0; c < NCLS; ++c) m = fmaxf(m, x[c]);
#pragma unroll
        for (int c = 0; c < NCLS; ++c) x[c] = expf(x[c] - m);   // independent
        float s = 0.f;
#pragma unroll
        for (int c = 0; c < NCLS; ++c) s += x[c];   // serial, reference order
        rowmax[(size_t)b * NANCH + n] = m;
        rowsum[(size_t)b * NANCH + n] = s;

        // ---- p = e/s (bit-identical to expf(x-m)/s); count per class ----
#pragma unroll
        for (int c = 1; c < NCLS; ++c) {
            x[c] = x[c] / s;
            if (x[c] > SCORE_TH) atomicAdd(&lcnt[c - 1], 1);
        }
    }
    __syncthreads();

    // One parallel global reservation per class (80 independent lane-atomics).
    if (tid < C1) {
        int cn = lcnt[tid];
        lbase[tid] = (cn > 0) ? atomicAdd(&cntg[b * C1 + tid], cn) : 0;
        lrank[tid] = 0;
    }
    __syncthreads();

    // Scatter candidates into reserved slots.
    if (act) {
#pragma unroll
        for (int c = 1; c < NCLS; ++c) {
            if (x[c] > SCORE_TH) {
                int r = atomicAdd(&lrank[c - 1], 1);
                int pos = lbase[c - 1] + r;
                if (pos < CAPB)
                    bucket[(size_t)(b * C1 + (c - 1)) * CAPB + pos] =
                        ((unsigned long long)__float_as_uint(x[c]) << 32)
                        | (unsigned long long)(0xFFFFFFFFu - (unsigned)n);
            }
        }
    }
}

// Kernel 2: per (b, class): histogram-select ~top-200, sort P=256, NMS.
__global__ __launch_bounds__(256) void ssd_class_nms(
    const float* __restrict__ plabel, const float* __restrict__ rowmax,
    const float* __restrict__ rowsum, const float* __restrict__ ltrb,
    const int* __restrict__ cntg, const unsigned long long* __restrict__ bucket,
    float* __restrict__ pcVals, float* __restrict__ pcBoxes) {
    __shared__ unsigned long long cand[CAP];          // 8 KB
    __shared__ unsigned int hist[NBINK2];             // 6 KB
    __shared__ int part[256];                         // 1 KB
    __shared__ float4 box4[MAXO];                     // 3.2 KB
    __shared__ float areas[MAXO], vs[MAXO];           // 1.6 KB
    __shared__ unsigned long long sup[MAXO][NWORD];   // 6.4 KB
    __shared__ unsigned long long keepw[NWORD], vmaskS[NWORD];
    __shared__ int cnt, fillcnt, cutbin, nztot;

    const int tid = threadIdx.x;
    const int b   = blockIdx.x / C1;
    const int cls = blockIdx.x % C1 + 1;   // skip background
    const int bc  = b * C1 + (cls - 1);

    for (int i = tid; i < NBINK2; i += 256) hist[i] = 0u;
    if (tid == 0) { cnt = 0; fillcnt = 0; cutbin = 1; }
    __syncthreads();

    const float* pl = plabel + ((size_t)b * NCLS + cls) * NANCH;
    const float* rm = rowmax + (size_t)b * NANCH;
    const float* rs = rowsum + (size_t)b * NANCH;
    const unsigned long long* bkt = bucket + (size_t)bc * CAPB;

    const int gcount = cntg[bc];
    const bool ovf = (gcount > CAPB);   // uniform; dead in practice
    int count, gathered;

    if (!ovf) {
        count = gcount;
        // Pass 1: histogram of bucket scores (bucket stays in L2; re-read later).
        for (int i = tid; i < count; i += 256) {
            unsigned bits = (unsigned)(bkt[i] >> 32);
            unsigned bin = ((bits - BINBASE) >> 15) + 1u;
            if (bin > NBINK2 - 1) bin = NBINK2 - 1;
            atomicAdd(&hist[bin], 1u);
        }
        __syncthreads();

        // Suffix-scan (thread owns 6 bins) -> exact cutoff bin B.
        int base = tid * 6;
        int loc = 0;
        for (int k = 0; k < 6; ++k) loc += (int)hist[base + k];
        part[tid] = loc;
        __syncthreads();
        for (int off = 1; off < 256; off <<= 1) {
            int v   = part[tid];
            int add = (tid + off < 256) ? part[tid + off] : 0;
            __syncthreads();
            part[tid] = v + add;
            __syncthreads();
        }
        if (tid == 0) nztot = part[0];
        {
            int suf = (tid + 1 < 256) ? part[tid + 1] : 0;
            int S = suf;
            for (int k = 5; k >= 0; --k) {
                int binv = (int)hist[base + k];
                int Sk = S + binv;
                int bin = base + k;
                if (bin >= 1 && Sk >= MAXO && S < MAXO) cutbin = bin;
                S = Sk;
            }
        }
        __syncthreads();
        int B = (nztot >= MAXO) ? cutbin : 1;

        // Pass 2: gather keys with bin >= B (top-200 is a subset; ~205 items).
        for (int i = tid; i < count; i += 256) {
            unsigned long long k = bkt[i];
            unsigned bits = (unsigned)(k >> 32);
            unsigned bin = ((bits - BINBASE) >> 15) + 1u;
            if (bin > NBINK2 - 1) bin = NBINK2 - 1;
            if ((int)bin >= B) {
                int pos = atomicAdd(&cnt, 1);
                if (pos < CAP) cand[pos] = k;
            }
        }
        __syncthreads();
        gathered = min(cnt, CAP);
    } else {
        // Overflow fallback (dead): full rescan, no select.
        for (int n = tid; n < NANCH; n += 256) {
            float p = expf(pl[n] - rm[n]) / rs[n];
            if (p > SCORE_TH) {
                int pos = atomicAdd(&cnt, 1);
                if (pos < CAP)
                    cand[pos] = ((unsigned long long)__float_as_uint(p) << 32)
                              | (unsigned long long)(0xFFFFFFFFu - (unsigned)n);
            }
        }
        __syncthreads();
        count = gathered = min(cnt, CAP);
    }

    int P = 256; while (P < gathered) P <<= 1;
    for (int i = gathered + tid; i < P; i += 256) cand[i] = 0ull;
    __syncthreads();
    bitonic_desc(cand, P, tid, 256);

    // If fewer than 200 positives, fill with smallest anchor indices having
    // prob <= TH (replicates top_k tie-breaking among zeros). Dead in practice.
    if (gathered < MAXO) {
        const int need = MAXO - gathered;
        for (int base2 = 0; base2 < NANCH; base2 += 256) {
            if (fillcnt >= need) break;   // uniform (LDS, synced)
            int n = base2 + tid;
            int flag = 0;
            if (n < NANCH) {
                float p = expf(pl[n] - rm[n]) / rs[n];
                flag = (p <= SCORE_TH) ? 1 : 0;
            }
            part[tid] = flag;
            __syncthreads();
            for (int off = 1; off < 256; off <<= 1) {
                int v  = part[tid];
                int vp = (tid >= off) ? part[tid - off] : 0;
                __syncthreads();
                part[tid] = v + vp;
                __syncthreads();
            }
            int excl = part[tid] - flag;
            if (flag && (fillcnt + excl) < need)
                cand[gathered + fillcnt + excl] =
                    (unsigned long long)(0xFFFFFFFFu - (unsigned)n);
            __syncthreads();
            if (tid == 0) fillcnt += part[255];
            __syncthreads();
        }
        __syncthreads();
    }

    // Gather top-200 boxes/scores/areas into LDS (one thread per t).
    if (tid < MAXO) {
#pragma clang fp contract(off)
        unsigned long long key = cand[tid];
        float sc   = __uint_as_float((unsigned)(key >> 32));
        unsigned n = 0xFFFFFFFFu - (unsigned)(key & 0xFFFFFFFFull);
        float4 bb =
            reinterpret_cast<const float4*>(ltrb)[(size_t)b * NANCH + n];
        box4[tid] = bb;
        areas[tid] = (bb.z - bb.x) * (bb.w - bb.y);
        vs[tid] = sc;
    }
    __syncthreads();

    // vs>0 bitmask via per-wave ballot (wave w = word w).
    {
        bool pred = (tid < MAXO) ? (vs[tid] > 0.f) : false;
        unsigned long long bal = __ballot(pred);
        if ((tid & 63) == 0) vmaskS[tid >> 6] = bal;
    }

    // Suppression bit-matrix, one i per thread: bit j set iff j>i && IoU>=TH.
    if (tid < MAXO) {
#pragma clang fp contract(off)
        const int i = tid;
        float4 bi = box4[i];
        float ai = areas[i];
        unsigned long long m0 = 0, m1 = 0, m2 = 0, m3 = 0;
        for (int j = i + 1; j < MAXO; ++j) {
            float4 bj = box4[j];
            float l = fmaxf(bi.x, bj.x);
            float t = fmaxf(bi.y, bj.y);
            float r = fminf(bi.z, bj.z);
            float d = fminf(bi.w, bj.w);
            float w = fmaxf(r - l, 0.f);
            float h = fmaxf(d - t, 0.f);
            float inter = w * h;
            float iou = inter / (ai + areas[j] - inter + 1e-12f);
            if (iou >= IOU_TH) {
                unsigned long long bit = 1ull << (j & 63);
                switch (j >> 6) {
                    case 0: m0 |= bit; break;
                    case 1: m1 |= bit; break;
                    case 2: m2 |= bit; break;
                    default: m3 |= bit; break;
                }
            }
        }
        sup[i][0] = m0; sup[i][1] = m1; sup[i][2] = m2; sup[i][3] = m3;
    }
    __syncthreads();

    // Serial greedy propagation on registers (reference fori_loop recurrence).
    if (tid == 0) {
        unsigned long long v0 = vmaskS[0], v1 = vmaskS[1],
                           v2 = vmaskS[2], v3 = vmaskS[3];
        unsigned long long k0 = ~0ull, k1 = ~0ull, k2 = ~0ull, k3 = ~0ull;
        for (int i = 0; i < MAXO; ++i) {
            unsigned long long kw = (i < 64) ? k0 : (i < 128) ? k1
                                  : (i < 192) ? k2 : k3;
            unsigned long long vw = (i < 64) ? v0 : (i < 128) ? v1
                                  : (i < 192) ? v2 : v3;
            if (((kw & vw) >> (i & 63)) & 1ull) {
                k0 &= ~sup[i][0]; k1 &= ~sup[i][1];
                k2 &= ~sup[i][2]; k3 &= ~sup[i][3];
            }
        }
        keepw[0] = k0; keepw[1] = k1; keepw[2] = k2; keepw[3] = k3;
    }
    __syncthreads();

    if (tid < MAXO) {
        bool kp = (keepw[tid >> 6] >> (tid & 63)) & 1ull;
        pcVals[(size_t)bc * MAXO + tid] = (kp && vs[tid] > 0.f) ? vs[tid] : 0.f;
        reinterpret_cast<float4*>(pcBoxes + (size_t)bc * MAXO * 4)[tid] =
            box4[tid];
    }
}

// Kernel 3: per image, exact top-200 over the 80*200 flat list via
// histogram cutoff selection + small exact sort.
__global__ __launch_bounds__(256) void ssd_final_topk(
    const float* __restrict__ pcVals, const float* __restrict__ pcBoxes,
    float* __restrict__ out) {
    __shared__ unsigned int hist[NBIN];
    __shared__ int part[256];
    __shared__ unsigned long long cand[CAP];
    __shared__ int cnt, cutbin, nztot;

    const int tid = threadIdx.x;
    const int b   = blockIdx.x;
    const int TOT = C1 * MAXO;   // 16000
    const float* pv = pcVals + (size_t)b * TOT;

    for (int i = tid; i < NBIN; i += 256) hist[i] = 0u;
    if (tid == 0) { cnt = 0; cutbin = 1; }
    __syncthreads();

    for (int g = tid; g < TOT; g += 256) {
        float v = pv[g];
        if (v > 0.f) {
            unsigned bits = __float_as_uint(v);
            unsigned bin = ((bits - BINBASE) >> 15) + 1u;
            if (bin > NBIN - 1) bin = NBIN - 1;
            atomicAdd(&hist[bin], 1u);
        }
    }
    __syncthreads();

    int base = tid * 8;
    int loc = 0;
    for (int k = 0; k < 8; ++k) loc += (int)hist[base + k];
    part[tid] = loc;
    __syncthreads();
    for (int off = 1; off < 256; off <<= 1) {
        int v   = part[tid];
        int add = (tid + off < 256) ? part[tid + off] : 0;
        __syncthreads();
        part[tid] = v + add;
        __syncthreads();
    }
    if (tid == 0) nztot = part[0];
    {
        int suf = (tid + 1 < 256) ? part[tid + 1] : 0;
        int S = suf;
        for (int k = 7; k >= 0; --k) {
            int binv = (int)hist[base + k];
            int Sk = S + binv;
            int bin = base + k;
            if (bin >= 1 && Sk >= MAXO && S < MAXO) cutbin = bin;
            S = Sk;
        }
    }
    __syncthreads();
    int B = (nztot >= MAXO) ? cutbin : 1;

    for (int g = tid; g < TOT; g += 256) {
        float v = pv[g];
        if (v > 0.f) {
            unsigned bits = __float_as_uint(v);
            unsigned bin = ((bits - BINBASE) >> 15) + 1u;
            if (bin > NBIN - 1) bin = NBIN - 1;
            if ((int)bin >= B) {
                int pos = atomicAdd(&cnt, 1);
                if (pos < CAP)
                    cand[pos] = ((unsigned long long)bits << 32)
                              | (unsigned long long)(0xFFFFFFFFu - (unsigned)g);
            }
        }
    }
    __syncthreads();
    int count = min(cnt, CAP);

    if (count < MAXO) {   // dead path
        if (tid == 0) {
            int c = count;
            for (int g = 0; g < TOT && c < MAXO; ++g) {
                if (!(pv[g] > 0.f)) {
                    cand[c++] = (unsigned long long)(0xFFFFFFFFu - (unsigned)g);
                }
            }
            cnt = c;
        }
        __syncthreads();
        count = min(cnt, CAP);
    }

    int P = 256; while (P < count) P <<= 1;
    for (int i = count + tid; i < P; i += 256) cand[i] = 0ull;
    __syncthreads();
    bitonic_desc(cand, P, tid, 256);

    for (int t = tid; t < MAXO; t += 256) {
        unsigned long long key = cand[t];
        float sc      = __uint_as_float((unsigned)(key >> 32));
        unsigned flat = 0xFFFFFFFFu - (unsigned)(key & 0xFFFFFFFFull);
        int cls = (int)(flat / MAXO) + 1;
        const float4 bb =
            reinterpret_cast<const float4*>(pcBoxes)[(size_t)b * TOT + flat];
        reinterpret_cast<float4*>(out)[(size_t)b * MAXO + t] = bb;
        out[(size_t)BATCH * MAXO * 4 + (size_t)b * MAXO + t] = (float)cls;
        out[(size_t)BATCH * MAXO * 5 + (size_t)b * MAXO + t] = sc;
    }
}

extern "C" void kernel_launch(void* const* d_in, const int* in_sizes, int n_in,
                              void* d_out, int out_size, void* d_ws,
                              size_t ws_size, hipStream_t stream) {
    const float* ploc   = (const float*)d_in[0];
    const float* plabel = (const float*)d_in[1];
    const float* dboxes = (const float*)d_in[2];
    float* out = (float*)d_out;

    float* ws      = (float*)d_ws;
    float* ltrb    = ws;                                   // B*N*4
    float* rowmax  = ltrb   + (size_t)BATCH * NANCH * 4;   // B*N
    float* rowsum  = rowmax + (size_t)BATCH * NANCH;       // B*N
    float* pcVals  = rowsum + (size_t)BATCH * NANCH;       // B*80*200
    float* pcBoxes = pcVals + (size_t)BATCH * C1 * MAXO;   // B*80*200*4
    int*   cntg    = (int*)(pcBoxes + (size_t)BATCH * C1 * MAXO * 4);
    unsigned long long* bucket =
        (unsigned long long*)(((char*)(cntg + BATCH * C1)) +
                              ((16 - (((size_t)(cntg + BATCH * C1)) & 15)) & 15));

    ssd_zero_cnt<<<(BATCH * C1 + 255) / 256, 256, 0, stream>>>(cntg);
    ssd_decode_stats<<<BATCH * NBLKA, APB, 0, stream>>>(
        ploc, plabel, dboxes, ltrb, rowmax, rowsum, cntg, bucket);
    ssd_class_nms<<<BATCH * C1, 256, 0, stream>>>(
        plabel, rowmax, rowsum, ltrb, cntg, bucket, pcVals, pcBoxes);
    ssd_final_topk<<<BATCH, 256, 0, stream>>>(pcVals, pcBoxes, out);
}

// Round 8
// 246.658 us; speedup vs baseline: 2.7980x; 1.0717x over previous
//
#include <hip/hip_runtime.h>
#include <math.h>

namespace {
constexpr int BATCH = 32;
constexpr int NANCH = 15130;
constexpr int NCLS  = 81;
constexpr int C1    = 80;          // foreground classes
constexpr int MAXO  = 200;
constexpr int APB   = 256;         // anchors per K1 block (= threads)
constexpr int NBLKA = (NANCH + APB - 1) / APB;   // 60
constexpr int CAP   = 1024;        // cand capacity (fallback sort buffer)
constexpr int CAPB  = 768;         // global bucket capacity (mean 434, sigma 20.5)
constexpr int NWORD = 4;           // 256 bits >= 200 for NMS bitmask
constexpr int NBIN  = 2048;        // histogram bins for final top-k select (K3)
constexpr int NBINK2 = 1536;       // histogram bins for K2 select (max used 1281)
constexpr unsigned BINBASE = 0x3D000000u;  // 0.03125f — below any score > 0.05
}

#define SCORE_TH 0.05f
#define IOU_TH   0.5f

typedef unsigned long long u64;

__device__ __forceinline__ u64 shflx64(u64 v, int mask) {
    int lo = __shfl_xor((int)(unsigned)(v & 0xffffffffull), mask, 64);
    int hi = __shfl_xor((int)(unsigned)(v >> 32), mask, 64);
    return ((u64)(unsigned)hi << 32) | (unsigned)lo;
}

// Descending bitonic sort of P (power of 2) u64 keys in LDS (fallback path).
// Key = (float_bits(score) << 32) | (0xFFFFFFFF - index)
// => order: score desc, then index asc (matches jax.lax.top_k stability).
// Comparison network => output independent of input permutation (keys distinct).
__device__ __forceinline__ void bitonic_desc(u64* keys, int P,
                                             int tid, int nthr) {
    for (int k = 2; k <= P; k <<= 1) {
        for (int j = k >> 1; j > 0; j >>= 1) {
            for (int i = tid; i < P; i += nthr) {
                int ixj = i ^ j;
                if (ixj > i) {
                    u64 a = keys[i], c = keys[ixj];
                    bool up = ((i & k) == 0);
                    if (up ? (a < c) : (a > c)) { keys[i] = c; keys[ixj] = a; }
                }
            }
            __syncthreads();
        }
    }
}

// Kernel 0: zero the per-(b,class) bucket counters.
__global__ __launch_bounds__(256) void ssd_zero_cnt(int* __restrict__ cntg) {
    int i = blockIdx.x * 256 + threadIdx.x;
    if (i < BATCH * C1) cntg[i] = 0;
}

// Kernel 1: one thread per anchor. 81 class logits live in REGISTERS.
// Register softmax (exact reference op order), decode, then the proven
// LDS-count -> one-global-reservation -> scatter bucket push.
__global__ __launch_bounds__(256) void ssd_decode_stats(
    const float* __restrict__ ploc, const float* __restrict__ plabel,
    const float* __restrict__ dboxes,
    float* __restrict__ ltrb, float* __restrict__ rowmax,
    float* __restrict__ rowsum,
    int* __restrict__ cntg, u64* __restrict__ bucket) {
#pragma clang fp contract(off)
    __shared__ int lcnt[C1], lbase[C1], lrank[C1];

    const int tid = threadIdx.x;
    const int b   = blockIdx.x / NBLKA;
    const int n0  = (blockIdx.x % NBLKA) * APB;
    const int n   = n0 + tid;
    const bool act = (n < NANCH);

    if (tid < C1) lcnt[tid] = 0;

    float x[NCLS];
    if (act) {
        const float* pl = ploc + (size_t)b * 4 * NANCH + n;
        float px = pl[0], py = pl[NANCH], pw = pl[2 * NANCH],
              ph = pl[3 * NANCH];
        float4 db = reinterpret_cast<const float4*>(dboxes)[n];
        float cx = px * 0.1f * db.z + db.x;
        float cy = py * 0.1f * db.w + db.y;
        float w  = expf(pw * 0.2f) * db.z;
        float h  = expf(ph * 0.2f) * db.w;
        float4 o;
        o.x = cx - 0.5f * w; o.y = cy - 0.5f * h;
        o.z = cx + 0.5f * w; o.w = cy + 0.5f * h;
        reinterpret_cast<float4*>(ltrb)[(size_t)b * NANCH + n] = o;

        const float* pb = plabel + (size_t)b * NCLS * NANCH + n;
#pragma unroll
        for (int c = 0; c < NCLS; ++c) x[c] = pb[(size_t)c * NANCH];

        float m = -INFINITY;
#pragma unroll
        for (int c = 0; c < NCLS; ++c) m = fmaxf(m, x[c]);
#pragma unroll
        for (int c = 0; c < NCLS; ++c) x[c] = expf(x[c] - m);
        float s = 0.f;
#pragma unroll
        for (int c = 0; c < NCLS; ++c) s += x[c];   // serial, reference order
        rowmax[(size_t)b * NANCH + n] = m;
        rowsum[(size_t)b * NANCH + n] = s;

#pragma unroll
        for (int c = 1; c < NCLS; ++c) {
            x[c] = x[c] / s;
            if (x[c] > SCORE_TH) atomicAdd(&lcnt[c - 1], 1);
        }
    }
    __syncthreads();

    if (tid < C1) {
        int cn = lcnt[tid];
        lbase[tid] = (cn > 0) ? atomicAdd(&cntg[b * C1 + tid], cn) : 0;
        lrank[tid] = 0;
    }
    __syncthreads();

    if (act) {
#pragma unroll
        for (int c = 1; c < NCLS; ++c) {
            if (x[c] > SCORE_TH) {
                int r = atomicAdd(&lrank[c - 1], 1);
                int pos = lbase[c - 1] + r;
                if (pos < CAPB)
                    bucket[(size_t)(b * C1 + (c - 1)) * CAPB + pos] =
                        ((u64)__float_as_uint(x[c]) << 32)
                        | (u64)(0xFFFFFFFFu - (unsigned)n);
            }
        }
    }
}

// Kernel 2: per (b, class): histogram-select ~top-200, register bitonic sort
// (shfl_xor for j<64, LDS only for j>=64), NMS with ctz-skip propagation.
__global__ __launch_bounds__(256) void ssd_class_nms(
    const float* __restrict__ plabel, const float* __restrict__ rowmax,
    const float* __restrict__ rowsum, const float* __restrict__ ltrb,
    const int* __restrict__ cntg, const u64* __restrict__ bucket,
    float* __restrict__ pcVals, float* __restrict__ pcBoxes) {
    __shared__ u64 cand[CAP];                 // 8 KB (gather + fallback sort)
    __shared__ unsigned int hist[NBINK2];     // 6 KB (reused as fill scratch)
    __shared__ float4 box4[MAXO];             // 3.2 KB
    __shared__ float areas[MAXO], vs[MAXO];   // 1.6 KB
    __shared__ u64 sup[MAXO][NWORD];          // 6.4 KB
    __shared__ u64 keepw[NWORD], vmaskS[NWORD];
    __shared__ int wtot[4];
    __shared__ int cnt, fillcnt, cutbin;

    const int tid  = threadIdx.x;
    const int lane = tid & 63;
    const int wv   = tid >> 6;
    const int b    = blockIdx.x / C1;
    const int cls  = blockIdx.x % C1 + 1;   // skip background
    const int bc   = b * C1 + (cls - 1);

    for (int i = tid; i < NBINK2; i += 256) hist[i] = 0u;
    if (tid == 0) { cnt = 0; fillcnt = 0; cutbin = 1; }
    __syncthreads();

    const float* pl = plabel + ((size_t)b * NCLS + cls) * NANCH;
    const float* rm = rowmax + (size_t)b * NANCH;
    const float* rs = rowsum + (size_t)b * NANCH;
    const u64* bkt = bucket + (size_t)bc * CAPB;

    const int gcount = cntg[bc];
    const bool ovf = (gcount > CAPB);   // uniform; dead in practice
    int gathered;

    if (!ovf) {
        const int count = gcount;
        // Pass 1: histogram of bucket scores.
        for (int i = tid; i < count; i += 256) {
            unsigned bits = (unsigned)(bkt[i] >> 32);
            unsigned bin = ((bits - BINBASE) >> 15) + 1u;
            if (bin > NBINK2 - 1) bin = NBINK2 - 1;
            atomicAdd(&hist[bin], 1u);
        }
        __syncthreads();

        // Per-thread group sum (6 bins), wave suffix-scan via shfl, combine.
        const int base = tid * 6;
        int loc = 0;
        for (int k = 0; k < 6; ++k) loc += (int)hist[base + k];
        int sfx = loc;   // inclusive suffix within wave
        for (int off = 1; off < 64; off <<= 1) {
            int t = __shfl_down(sfx, off, 64);
            if (lane + off < 64) sfx += t;
        }
        if (lane == 0) wtot[wv] = sfx;
        __syncthreads();
        int crossSuf = 0;
        for (int w2 = wv + 1; w2 < 4; ++w2) crossSuf += wtot[w2];
        const int nztot = wtot[0] + wtot[1] + wtot[2] + wtot[3];
        {
            int S = (sfx - loc) + crossSuf;   // suffix beyond my 6-bin group
            for (int k = 5; k >= 0; --k) {
                int binv = (int)hist[base + k];
                int Sk = S + binv;
                int bin = base + k;
                if (bin >= 1 && Sk >= MAXO && S < MAXO) cutbin = bin;
                S = Sk;
            }
        }
        __syncthreads();
        const int B = (nztot >= MAXO) ? cutbin : 1;

        // Pass 2: gather keys with bin >= B (top-200 is a subset; ~205 items).
        for (int i = tid; i < count; i += 256) {
            u64 k = bkt[i];
            unsigned bits = (unsigned)(k >> 32);
            unsigned bin = ((bits - BINBASE) >> 15) + 1u;
            if (bin > NBINK2 - 1) bin = NBINK2 - 1;
            if ((int)bin >= B) {
                int pos = atomicAdd(&cnt, 1);
                if (pos < CAP) cand[pos] = k;
            }
        }
        __syncthreads();
        gathered = min(cnt, CAP);
    } else {
        // Overflow fallback (dead): full rescan, no select.
        for (int n = tid; n < NANCH; n += 256) {
            float p = expf(pl[n] - rm[n]) / rs[n];
            if (p > SCORE_TH) {
                int pos = atomicAdd(&cnt, 1);
                if (pos < CAP)
                    cand[pos] = ((u64)__float_as_uint(p) << 32)
                              | (u64)(0xFFFFFFFFu - (unsigned)n);
            }
        }
        __syncthreads();
        gathered = min(cnt, CAP);
    }

    // ---- sort: register bitonic (gathered <= 256, the always case) ----
    u64 key;
    if (gathered <= 256) {
        key = (tid < gathered) ? cand[tid] : 0ull;
        for (int k = 2; k <= 256; k <<= 1) {
            for (int j = k >> 1; j > 0; j >>= 1) {
                if (j < 64) {
                    u64 pv = shflx64(key, j);
                    bool up = ((tid & k) == 0);
                    bool lt = ((tid & j) == 0);
                    u64 mx = (key > pv) ? key : pv;
                    u64 mn = (key > pv) ? pv : key;
                    key = (up == lt) ? mx : mn;
                } else {
                    cand[tid] = key;
                    __syncthreads();
                    u64 pv = cand[tid ^ j];
                    bool up = ((tid & k) == 0);
                    bool lt = ((tid & j) == 0);
                    u64 mx = (key > pv) ? key : pv;
                    u64 mn = (key > pv) ? pv : key;
                    key = (up == lt) ? mx : mn;
                    __syncthreads();
                }
            }
        }
    } else {
        // Fallback (dead): LDS bitonic.
        int P = 256; while (P < gathered) P <<= 1;
        for (int i = gathered + tid; i < P; i += 256) cand[i] = 0ull;
        __syncthreads();
        bitonic_desc(cand, P, tid, 256);
        key = cand[tid];
    }

    // If fewer than 200 positives, fill with smallest anchor indices having
    // prob <= TH (replicates top_k tie-breaking among zeros). Dead in practice.
    if (gathered < MAXO) {
        int* scanb = (int*)hist;   // reuse: histogram no longer needed
        cand[tid] = key;
        __syncthreads();
        const int need = MAXO - gathered;
        for (int base2 = 0; base2 < NANCH; base2 += 256) {
            if (fillcnt >= need) break;   // uniform (LDS, synced)
            int n = base2 + tid;
            int flag = 0;
            if (n < NANCH) {
                float p = expf(pl[n] - rm[n]) / rs[n];
                flag = (p <= SCORE_TH) ? 1 : 0;
            }
            scanb[tid] = flag;
            __syncthreads();
            for (int off = 1; off < 256; off <<= 1) {
                int v  = scanb[tid];
                int vp = (tid >= off) ? scanb[tid - off] : 0;
                __syncthreads();
                scanb[tid] = v + vp;
                __syncthreads();
            }
            int excl = scanb[tid] - flag;
            if (flag && (fillcnt + excl) < need)
                cand[gathered + fillcnt + excl] =
                    (u64)(0xFFFFFFFFu - (unsigned)n);
            __syncthreads();
            if (tid == 0) fillcnt += scanb[255];
            __syncthreads();
        }
        __syncthreads();
        key = cand[tid];
    }

    // Gather top-200 boxes/scores/areas into LDS from register key.
    if (tid < MAXO) {
#pragma clang fp contract(off)
        float sc   = __uint_as_float((unsigned)(key >> 32));
        unsigned n = 0xFFFFFFFFu - (unsigned)(key & 0xFFFFFFFFull);
        float4 bb =
            reinterpret_cast<const float4*>(ltrb)[(size_t)b * NANCH + n];
        box4[tid] = bb;
        areas[tid] = (bb.z - bb.x) * (bb.w - bb.y);
        vs[tid] = sc;
    }
    // vs>0 bitmask via per-wave ballot (wave w = word w).
    {
        bool pred = (tid < MAXO) ?
            (__uint_as_float((unsigned)(key >> 32)) > 0.f) : false;
        u64 bal = __ballot(pred);
        if (lane == 0) vmaskS[wv] = bal;
    }
    __syncthreads();

    // Suppression bit-matrix, one i per thread: bit j set iff j>i && IoU>=TH.
    if (tid < MAXO) {
#pragma clang fp contract(off)
        const int i = tid;
        float4 bi = box4[i];
        float ai = areas[i];
        u64 m0 = 0, m1 = 0, m2 = 0, m3 = 0;
        for (int j = i + 1; j < MAXO; ++j) {
            float4 bj = box4[j];
            float l = fmaxf(bi.x, bj.x);
            float t = fmaxf(bi.y, bj.y);
            float r = fminf(bi.z, bj.z);
            float d = fminf(bi.w, bj.w);
            float w = fmaxf(r - l, 0.f);
            float h = fmaxf(d - t, 0.f);
            float inter = w * h;
            float iou = inter / (ai + areas[j] - inter + 1e-12f);
            if (iou >= IOU_TH) {
                u64 bit = 1ull << (j & 63);
                switch (j >> 6) {
                    case 0: m0 |= bit; break;
                    case 1: m1 |= bit; break;
                    case 2: m2 |= bit; break;
                    default: m3 |= bit; break;
                }
            }
        }
        sup[i][0] = m0; sup[i][1] = m1; sup[i][2] = m2; sup[i][3] = m3;
    }
    __syncthreads();

    // Greedy propagation, skipping non-kept i via ctz (same recurrence:
    // sup[i] only sets bits > i, so processed bits are never revisited).
    if (tid == 0) {
        u64 v0 = vmaskS[0], v1 = vmaskS[1], v2 = vmaskS[2], v3 = vmaskS[3];
        u64 k0 = ~0ull, k1 = ~0ull, k2 = ~0ull, k3 = ~0ull;
        for (int w = 0; w < 4; ++w) {
            u64 vw = (w == 0) ? v0 : (w == 1) ? v1 : (w == 2) ? v2 : v3;
            u64 kw = (w == 0) ? k0 : (w == 1) ? k1 : (w == 2) ? k2 : k3;
            u64 cur = kw & vw;
            while (cur) {
                int bit = __builtin_ctzll(cur);
                int i = w * 64 + bit;
                k0 &= ~sup[i][0]; k1 &= ~sup[i][1];
                k2 &= ~sup[i][2]; k3 &= ~sup[i][3];
                kw = (w == 0) ? k0 : (w == 1) ? k1 : (w == 2) ? k2 : k3;
                u64 above = (bit == 63) ? 0ull : (~0ull << (bit + 1));
                cur = kw & vw & above;
            }
        }
        keepw[0] = k0; keepw[1] = k1; keepw[2] = k2; keepw[3] = k3;
    }
    __syncthreads();

    if (tid < MAXO) {
        bool kp = (keepw[tid >> 6] >> (tid & 63)) & 1ull;
        pcVals[(size_t)bc * MAXO + tid] = (kp && vs[tid] > 0.f) ? vs[tid] : 0.f;
        reinterpret_cast<float4*>(pcBoxes + (size_t)bc * MAXO * 4)[tid] =
            box4[tid];
    }
}

// Kernel 3: per image, exact top-200 over the 80*200 flat list via
// histogram cutoff selection + small exact sort.
__global__ __launch_bounds__(256) void ssd_final_topk(
    const float* __restrict__ pcVals, const float* __restrict__ pcBoxes,
    float* __restrict__ out) {
    __shared__ unsigned int hist[NBIN];
    __shared__ int part[256];
    __shared__ u64 cand[CAP];
    __shared__ int cnt, cutbin, nztot;

    const int tid = threadIdx.x;
    const int b   = blockIdx.x;
    const int TOT = C1 * MAXO;   // 16000
    const float* pv = pcVals + (size_t)b * TOT;

    for (int i = tid; i < NBIN; i += 256) hist[i] = 0u;
    if (tid == 0) { cnt = 0; cutbin = 1; }
    __syncthreads();

    for (int g = tid; g < TOT; g += 256) {
        float v = pv[g];
        if (v > 0.f) {
            unsigned bits = __float_as_uint(v);
            unsigned bin = ((bits - BINBASE) >> 15) + 1u;
            if (bin > NBIN - 1) bin = NBIN - 1;
            atomicAdd(&hist[bin], 1u);
        }
    }
    __syncthreads();

    int base = tid * 8;
    int loc = 0;
    for (int k = 0; k < 8; ++k) loc += (int)hist[base + k];
    part[tid] = loc;
    __syncthreads();
    for (int off = 1; off < 256; off <<= 1) {
        int v   = part[tid];
        int add = (tid + off < 256) ? part[tid + off] : 0;
        __syncthreads();
        part[tid] = v + add;
        __syncthreads();
    }
    if (tid == 0) nztot = part[0];
    {
        int suf = (tid + 1 < 256) ? part[tid + 1] : 0;
        int S = suf;
        for (int k = 7; k >= 0; --k) {
            int binv = (int)hist[base + k];
            int Sk = S + binv;
            int bin = base + k;
            if (bin >= 1 && Sk >= MAXO && S < MAXO) cutbin = bin;
            S = Sk;
        }
    }
    __syncthreads();
    int B = (nztot >= MAXO) ? cutbin : 1;

    for (int g = tid; g < TOT; g += 256) {
        float v = pv[g];
        if (v > 0.f) {
            unsigned bits = __float_as_uint(v);
            unsigned bin = ((bits - BINBASE) >> 15) + 1u;
            if (bin > NBIN - 1) bin = NBIN - 1;
            if ((int)bin >= B) {
                int pos = atomicAdd(&cnt, 1);
                if (pos < CAP)
                    cand[pos] = ((u64)bits << 32)
                              | (u64)(0xFFFFFFFFu - (unsigned)g);
            }
        }
    }
    __syncthreads();
    int count = min(cnt, CAP);

    if (count < MAXO) {   // dead path
        if (tid == 0) {
            int c = count;
            for (int g = 0; g < TOT && c < MAXO; ++g) {
                if (!(pv[g] > 0.f)) {
                    cand[c++] = (u64)(0xFFFFFFFFu - (unsigned)g);
                }
            }
            cnt = c;
        }
        __syncthreads();
        count = min(cnt, CAP);
    }

    int P = 256; while (P < count) P <<= 1;
    for (int i = count + tid; i < P; i += 256) cand[i] = 0ull;
    __syncthreads();
    bitonic_desc(cand, P, tid, 256);

    for (int t = tid; t < MAXO; t += 256) {
        u64 key = cand[t];
        float sc      = __uint_as_float((unsigned)(key >> 32));
        unsigned flat = 0xFFFFFFFFu - (unsigned)(key & 0xFFFFFFFFull);
        int cls = (int)(flat / MAXO) + 1;
        const float4 bb =
            reinterpret_cast<const float4*>(pcBoxes)[(size_t)b * TOT + flat];
        reinterpret_cast<float4*>(out)[(size_t)b * MAXO + t] = bb;
        out[(size_t)BATCH * MAXO * 4 + (size_t)b * MAXO + t] = (float)cls;
        out[(size_t)BATCH * MAXO * 5 + (size_t)b * MAXO + t] = sc;
    }
}

extern "C" void kernel_launch(void* const* d_in, const int* in_sizes, int n_in,
                              void* d_out, int out_size, void* d_ws,
                              size_t ws_size, hipStream_t stream) {
    const float* ploc   = (const float*)d_in[0];
    const float* plabel = (const float*)d_in[1];
    const float* dboxes = (const float*)d_in[2];
    float* out = (float*)d_out;

    float* ws      = (float*)d_ws;
    float* ltrb    = ws;                                   // B*N*4
    float* rowmax  = ltrb   + (size_t)BATCH * NANCH * 4;   // B*N
    float* rowsum  = rowmax + (size_t)BATCH * NANCH;       // B*N
    float* pcVals  = rowsum + (size_t)BATCH * NANCH;       // B*80*200
    float* pcBoxes = pcVals + (size_t)BATCH * C1 * MAXO;   // B*80*200*4
    int*   cntg    = (int*)(pcBoxes + (size_t)BATCH * C1 * MAXO * 4);
    u64* bucket =
        (u64*)(((char*)(cntg + BATCH * C1)) +
               ((16 - (((size_t)(cntg + BATCH * C1)) & 15)) & 15));

    ssd_zero_cnt<<<(BATCH * C1 + 255) / 256, 256, 0, stream>>>(cntg);
    ssd_decode_stats<<<BATCH * NBLKA, APB, 0, stream>>>(
        ploc, plabel, dboxes, ltrb, rowmax, rowsum, cntg, bucket);
    ssd_class_nms<<<BATCH * C1, 256, 0, stream>>>(
        plabel, rowmax, rowsum, ltrb, cntg, bucket, pcVals, pcBoxes);
    ssd_final_topk<<<BATCH, 256, 0, stream>>>(pcVals, pcBoxes, out);
}